// Round 2
// baseline (8363.966 us; speedup 1.0000x reference)
//
#include <hip/hip_runtime.h>

#define S_LEN  4096
#define DMODEL 512
#define NH     8
#define HD     64

typedef _Float16 f16x8 __attribute__((ext_vector_type(8)));
typedef float    f32x4 __attribute__((ext_vector_type(4)));

static __device__ __forceinline__ unsigned short f2h(float x) {
  return __builtin_bit_cast(unsigned short, (_Float16)x);
}
static __device__ __forceinline__ float h2f(unsigned short x) {
  return (float)__builtin_bit_cast(_Float16, x);
}

// ---------------------------------------------------------------------------
// Weight transpose + fp32->fp16 convert: Wt[n][k] = (fp16) W[k][n]
// grid (8,8,4) block 256
// ---------------------------------------------------------------------------
__global__ __launch_bounds__(256) void wtrans_kernel(
    const float* __restrict__ w0, const float* __restrict__ w1,
    const float* __restrict__ w2, const float* __restrict__ w3,
    unsigned short* __restrict__ o0, unsigned short* __restrict__ o1,
    unsigned short* __restrict__ o2, unsigned short* __restrict__ o3)
{
  __shared__ unsigned short T[64 * 72];   // T[n_local][k_local], pad 72
  const float* W; unsigned short* O;
  switch (blockIdx.z) {
    case 0:  W = w0; O = o0; break;
    case 1:  W = w1; O = o1; break;
    case 2:  W = w2; O = o2; break;
    default: W = w3; O = o3; break;
  }
  const int tid = threadIdx.x;
  const int k0 = blockIdx.x * 64, n0 = blockIdx.y * 64;
  const int c4 = (tid & 15) * 4;
#pragma unroll
  for (int rp = 0; rp < 4; ++rp) {
    int r = rp * 16 + (tid >> 4);
    float4 x = *(const float4*)(W + (k0 + r) * DMODEL + n0 + c4);
    T[(c4 + 0) * 72 + r] = f2h(x.x);
    T[(c4 + 1) * 72 + r] = f2h(x.y);
    T[(c4 + 2) * 72 + r] = f2h(x.z);
    T[(c4 + 3) * 72 + r] = f2h(x.w);
  }
  __syncthreads();
#pragma unroll
  for (int it = 0; it < 2; ++it) {
    int i = tid + it * 256;
    int nl = i >> 3, c = i & 7;
    *(f16x8*)&O[(n0 + nl) * DMODEL + k0 + c * 8] = *(const f16x8*)&T[nl * 72 + c * 8];
  }
}

// ---------------------------------------------------------------------------
// GEMM: C[4096][512] = A[4096][512] @ Bt[512][512]^T (+bias)
// A fp32 (converted during staging) or fp16; C fp32 or fp16.
// 64x64 tile, BK=32, 4 waves 2x2, mfma_f32_16x16x32_f16.
// grid (64,8) block 256
// ---------------------------------------------------------------------------
__global__ __launch_bounds__(256) void gemm_kernel(
    const void* __restrict__ Av, const unsigned short* __restrict__ Bt,
    void* __restrict__ Cv, const float* __restrict__ bias,
    int a_fp32, int c_fp32)
{
  constexpr int K = DMODEL, N = DMODEL;
  __shared__ unsigned short As[64 * 32];
  __shared__ unsigned short Bs[64 * 32];
  const int tid  = threadIdx.x;
  const int lane = tid & 63;
  const int wid  = tid >> 6;
  const int quad = lane >> 4, l16 = lane & 15;
  const int m0 = blockIdx.x * 64, n0 = blockIdx.y * 64;
  const int wm = (wid >> 1) * 32, wn = (wid & 1) * 32;
  const int r  = tid >> 2, ck = (tid & 3) * 8;   // staging: row, k-offset
  f32x4 acc[2][2] = {};

  for (int k0 = 0; k0 < K; k0 += 32) {
    __syncthreads();
    if (a_fp32) {
      const float* p = (const float*)Av + (m0 + r) * K + k0 + ck;
      float4 x = *(const float4*)p;
      float4 y = *(const float4*)(p + 4);
      f16x8 av;
      av[0] = (_Float16)x.x; av[1] = (_Float16)x.y;
      av[2] = (_Float16)x.z; av[3] = (_Float16)x.w;
      av[4] = (_Float16)y.x; av[5] = (_Float16)y.y;
      av[6] = (_Float16)y.z; av[7] = (_Float16)y.w;
      *(f16x8*)&As[r * 32 + ck] = av;
    } else {
      *(f16x8*)&As[r * 32 + ck] =
          *(const f16x8*)((const unsigned short*)Av + (m0 + r) * K + k0 + ck);
    }
    *(f16x8*)&Bs[r * 32 + ck] = *(const f16x8*)(Bt + (n0 + r) * K + k0 + ck);
    __syncthreads();

    f16x8 a0 = *(const f16x8*)&As[(wm + l16) * 32 + quad * 8];
    f16x8 a1 = *(const f16x8*)&As[(wm + 16 + l16) * 32 + quad * 8];
    f16x8 b0 = *(const f16x8*)&Bs[(wn + l16) * 32 + quad * 8];
    f16x8 b1 = *(const f16x8*)&Bs[(wn + 16 + l16) * 32 + quad * 8];
    acc[0][0] = __builtin_amdgcn_mfma_f32_16x16x32_f16(a0, b0, acc[0][0], 0, 0, 0);
    acc[0][1] = __builtin_amdgcn_mfma_f32_16x16x32_f16(a0, b1, acc[0][1], 0, 0, 0);
    acc[1][0] = __builtin_amdgcn_mfma_f32_16x16x32_f16(a1, b0, acc[1][0], 0, 0, 0);
    acc[1][1] = __builtin_amdgcn_mfma_f32_16x16x32_f16(a1, b1, acc[1][1], 0, 0, 0);
  }

#pragma unroll
  for (int mt = 0; mt < 2; ++mt)
#pragma unroll
    for (int nt = 0; nt < 2; ++nt) {
      int col = n0 + wn + nt * 16 + l16;
      float bv = bias ? bias[col] : 0.f;
#pragma unroll
      for (int g = 0; g < 4; ++g) {
        int row = m0 + wm + mt * 16 + quad * 4 + g;   // C/D: row = quad*4+reg
        float val = acc[mt][nt][g] + bv;
        if (c_fp32) ((float*)Cv)[row * N + col] = val;
        else        ((unsigned short*)Cv)[row * N + col] = f2h(val);
      }
    }
}

// ---------------------------------------------------------------------------
// VALU flash attention (bisection round: no MFMA, no LDS, no layout tricks).
// One wave per (q-row, head): lane = head-dim. fp32 online softmax.
// grid (1024, 8) block 256 (4 waves).
// ---------------------------------------------------------------------------
__global__ __launch_bounds__(256) void attn_valu_kernel(
    const unsigned short* __restrict__ Qb, const unsigned short* __restrict__ Kb,
    const unsigned short* __restrict__ Vb, unsigned short* __restrict__ Ob)
{
  const int tid  = threadIdx.x;
  const int lane = tid & 63;
  const int wid  = tid >> 6;
  const int row  = blockIdx.x * 4 + wid;
  const int hc   = blockIdx.y * HD;

  const float qd = h2f(Qb[row * DMODEL + hc + lane]);
  float m = -1e30f, l = 0.f, o = 0.f;

  for (int n = 0; n < S_LEN; ++n) {
    float part = qd * h2f(Kb[n * DMODEL + hc + lane]);
    part += __shfl_xor(part, 1);
    part += __shfl_xor(part, 2);
    part += __shfl_xor(part, 4);
    part += __shfl_xor(part, 8);
    part += __shfl_xor(part, 16);
    part += __shfl_xor(part, 32);
    const float s  = part * 0.125f;          // /sqrt(DK)
    const float mn = fmaxf(m, s);
    const float alpha = __expf(m - mn);
    const float p     = __expf(s - mn);
    const float vd = h2f(Vb[n * DMODEL + hc + lane]);
    l = l * alpha + p;
    o = o * alpha + p * vd;
    m = mn;
  }
  Ob[row * DMODEL + hc + lane] = f2h(o / l);
}

// ---------------------------------------------------------------------------
extern "C" void kernel_launch(void* const* d_in, const int* in_sizes, int n_in,
                              void* d_out, int out_size, void* d_ws, size_t ws_size,
                              hipStream_t stream) {
  const float* q  = (const float*)d_in[0];
  const float* k  = (const float*)d_in[1];
  const float* v  = (const float*)d_in[2];
  const float* Wq = (const float*)d_in[3];
  const float* Wk = (const float*)d_in[4];
  const float* Wv = (const float*)d_in[5];
  const float* Wo = (const float*)d_in[6];
  const float* bo = (const float*)d_in[7];

  unsigned short* ws  = (unsigned short*)d_ws;
  unsigned short* Wqt = ws;                  // 512*512 fp16 each
  unsigned short* Wkt = Wqt + 262144;
  unsigned short* Wvt = Wkt + 262144;
  unsigned short* Wot = Wvt + 262144;
  unsigned short* Qb  = Wot + 262144;        // 4096*512 fp16 each
  unsigned short* Kb  = Qb + 2097152;
  unsigned short* Vb  = Kb + 2097152;
  unsigned short* Ab  = Vb + 2097152;        // attention output
  unsigned short* O1  = Kb;                  // fc1 output aliases Kb (dead after attn)
  // peak ws use: (4*262144 + 4*2097152) * 2 B = 18.9 MB

  wtrans_kernel<<<dim3(8, 8, 4), 256, 0, stream>>>(Wq, Wk, Wv, Wo, Wqt, Wkt, Wvt, Wot);

  gemm_kernel<<<dim3(64, 8), 256, 0, stream>>>(q, Wqt, Qb, nullptr, 1, 0);
  gemm_kernel<<<dim3(64, 8), 256, 0, stream>>>(k, Wkt, Kb, nullptr, 1, 0);
  gemm_kernel<<<dim3(64, 8), 256, 0, stream>>>(v, Wvt, Vb, nullptr, 1, 0);

  attn_valu_kernel<<<dim3(S_LEN / 4, NH), 256, 0, stream>>>(Qb, Kb, Vb, Ab);

  gemm_kernel<<<dim3(64, 8), 256, 0, stream>>>(Ab, Wot, O1, bo, 0, 0);
  gemm_kernel<<<dim3(64, 8), 256, 0, stream>>>(O1, Wot, d_out, bo, 0, 1);
}

// Round 4
// 579.082 us; speedup vs baseline: 14.4435x; 14.4435x over previous
//
#include <hip/hip_runtime.h>

#define S_LEN  4096
#define DMODEL 512
#define NH     8
#define HD     64

typedef _Float16 f16x8 __attribute__((ext_vector_type(8)));
typedef _Float16 f16x4 __attribute__((ext_vector_type(4)));
typedef float    f32x4 __attribute__((ext_vector_type(4)));

static __device__ __forceinline__ unsigned short f2h(float x) {
  return __builtin_bit_cast(unsigned short, (_Float16)x);
}
static __device__ __forceinline__ float h2f(unsigned short x) {
  return (float)__builtin_bit_cast(_Float16, x);
}

// ---------------------------------------------------------------------------
// Weight transpose + fp32->fp16 convert: Wt[n][k] = (fp16) W[k][n]
// grid (8,8,4) block 256
// ---------------------------------------------------------------------------
__global__ __launch_bounds__(256) void wtrans_kernel(
    const float* __restrict__ w0, const float* __restrict__ w1,
    const float* __restrict__ w2, const float* __restrict__ w3,
    unsigned short* __restrict__ o0, unsigned short* __restrict__ o1,
    unsigned short* __restrict__ o2, unsigned short* __restrict__ o3)
{
  __shared__ unsigned short T[64 * 72];   // T[n_local][k_local], pad 72
  const float* W; unsigned short* O;
  switch (blockIdx.z) {
    case 0:  W = w0; O = o0; break;
    case 1:  W = w1; O = o1; break;
    case 2:  W = w2; O = o2; break;
    default: W = w3; O = o3; break;
  }
  const int tid = threadIdx.x;
  const int k0 = blockIdx.x * 64, n0 = blockIdx.y * 64;
  const int c4 = (tid & 15) * 4;
#pragma unroll
  for (int rp = 0; rp < 4; ++rp) {
    int r = rp * 16 + (tid >> 4);
    float4 x = *(const float4*)(W + (k0 + r) * DMODEL + n0 + c4);
    T[(c4 + 0) * 72 + r] = f2h(x.x);
    T[(c4 + 1) * 72 + r] = f2h(x.y);
    T[(c4 + 2) * 72 + r] = f2h(x.z);
    T[(c4 + 3) * 72 + r] = f2h(x.w);
  }
  __syncthreads();
#pragma unroll
  for (int it = 0; it < 2; ++it) {
    int i = tid + it * 256;
    int nl = i >> 3, c = i & 7;
    *(f16x8*)&O[(n0 + nl) * DMODEL + k0 + c * 8] = *(const f16x8*)&T[nl * 72 + c * 8];
  }
}

// ---------------------------------------------------------------------------
// GEMM: C[4096][512] = A[4096][512] @ Bt[512][512]^T (+bias)
// A fp32 (converted during staging) or fp16; C fp32 or fp16.
// 64x64 tile, BK=32, 4 waves 2x2, mfma_f32_16x16x32_f16.
// grid (64,8) block 256
// ---------------------------------------------------------------------------
__global__ __launch_bounds__(256) void gemm_kernel(
    const void* __restrict__ Av, const unsigned short* __restrict__ Bt,
    void* __restrict__ Cv, const float* __restrict__ bias,
    int a_fp32, int c_fp32)
{
  constexpr int K = DMODEL, N = DMODEL;
  __shared__ unsigned short As[64 * 32];
  __shared__ unsigned short Bs[64 * 32];
  const int tid  = threadIdx.x;
  const int lane = tid & 63;
  const int wid  = tid >> 6;
  const int quad = lane >> 4, l16 = lane & 15;
  const int m0 = blockIdx.x * 64, n0 = blockIdx.y * 64;
  const int wm = (wid >> 1) * 32, wn = (wid & 1) * 32;
  const int r  = tid >> 2, ck = (tid & 3) * 8;   // staging: row, k-offset
  f32x4 acc[2][2] = {};

  for (int k0 = 0; k0 < K; k0 += 32) {
    __syncthreads();
    if (a_fp32) {
      const float* p = (const float*)Av + (m0 + r) * K + k0 + ck;
      float4 x = *(const float4*)p;
      float4 y = *(const float4*)(p + 4);
      f16x8 av;
      av[0] = (_Float16)x.x; av[1] = (_Float16)x.y;
      av[2] = (_Float16)x.z; av[3] = (_Float16)x.w;
      av[4] = (_Float16)y.x; av[5] = (_Float16)y.y;
      av[6] = (_Float16)y.z; av[7] = (_Float16)y.w;
      *(f16x8*)&As[r * 32 + ck] = av;
    } else {
      *(f16x8*)&As[r * 32 + ck] =
          *(const f16x8*)((const unsigned short*)Av + (m0 + r) * K + k0 + ck);
    }
    *(f16x8*)&Bs[r * 32 + ck] = *(const f16x8*)(Bt + (n0 + r) * K + k0 + ck);
    __syncthreads();

    f16x8 a0 = *(const f16x8*)&As[(wm + l16) * 32 + quad * 8];
    f16x8 a1 = *(const f16x8*)&As[(wm + 16 + l16) * 32 + quad * 8];
    f16x8 b0 = *(const f16x8*)&Bs[(wn + l16) * 32 + quad * 8];
    f16x8 b1 = *(const f16x8*)&Bs[(wn + 16 + l16) * 32 + quad * 8];
    acc[0][0] = __builtin_amdgcn_mfma_f32_16x16x32_f16(a0, b0, acc[0][0], 0, 0, 0);
    acc[0][1] = __builtin_amdgcn_mfma_f32_16x16x32_f16(a0, b1, acc[0][1], 0, 0, 0);
    acc[1][0] = __builtin_amdgcn_mfma_f32_16x16x32_f16(a1, b0, acc[1][0], 0, 0, 0);
    acc[1][1] = __builtin_amdgcn_mfma_f32_16x16x32_f16(a1, b1, acc[1][1], 0, 0, 0);
  }

#pragma unroll
  for (int mt = 0; mt < 2; ++mt)
#pragma unroll
    for (int nt = 0; nt < 2; ++nt) {
      int col = n0 + wn + nt * 16 + l16;
      float bv = bias ? bias[col] : 0.f;
#pragma unroll
      for (int g = 0; g < 4; ++g) {
        int row = m0 + wm + mt * 16 + quad * 4 + g;   // C/D: row = quad*4+reg
        float val = acc[mt][nt][g] + bv;
        if (c_fp32) ((float*)Cv)[row * N + col] = val;
        else        ((unsigned short*)Cv)[row * N + col] = f2h(val);
      }
    }
}

// ---------------------------------------------------------------------------
// BISECTION attention: MFMA QK^T + online softmax (verbatim from round 3),
// but PV done in VALU from plain-staged V. grid (64, 8), block 256.
// ---------------------------------------------------------------------------
__global__ __launch_bounds__(256) void attn_kernel(
    const unsigned short* __restrict__ Qb, const unsigned short* __restrict__ Kb,
    const unsigned short* __restrict__ Vb, unsigned short* __restrict__ Ob)
{
  __shared__ unsigned short Ks[64 * 64];   // K[n][k], 8 KB
  __shared__ unsigned short Vs[64 * 72];   // V[n][d] plain, pad 72
  __shared__ unsigned short Ps[4][16 * 72];// per-wave P, pad 72

  const int tid  = threadIdx.x;
  const int lane = tid & 63;
  const int wid  = tid >> 6;
  const int quad = lane >> 4, l16 = lane & 15;
  const int qb = blockIdx.x, h = blockIdx.y;
  const int hc = h * HD;

  // Persistent Q A-fragments: rows qb*64 + wid*16 + (lane&15), k = quad*8..+8 (+32)
  const int qrow = qb * 64 + wid * 16 + l16;
  const f16x8 aq0 = *(const f16x8*)(Qb + qrow * DMODEL + hc + quad * 8);
  const f16x8 aq1 = *(const f16x8*)(Qb + qrow * DMODEL + hc + 32 + quad * 8);

  // VALU O accumulator: row quad*4+g, col l16*4+i
  float o4[4][4] = {};
  float m_run[4], l_run[4];
#pragma unroll
  for (int i = 0; i < 4; ++i) { m_run[i] = -1e30f; l_run[i] = 0.f; }

  for (int kb = 0; kb < S_LEN / 64; ++kb) {
    __syncthreads();
    // ---- stage K[n][k] and V[n][d] plain
    {
      int i = tid;
#pragma unroll
      for (int it = 0; it < 2; ++it, i += 256) {
        int n = i >> 3, c = i & 7;
        *(f16x8*)&Ks[n * 64 + c * 8] =
            *(const f16x8*)(Kb + (kb * 64 + n) * DMODEL + hc + c * 8);
        *(f16x8*)&Vs[n * 72 + c * 8] =
            *(const f16x8*)(Vb + (kb * 64 + n) * DMODEL + hc + c * 8);
      }
    }
    __syncthreads();

    // ---- S = Q K^T (raw logits, fp32 accs)
    f32x4 s[4];
#pragma unroll
    for (int nt = 0; nt < 4; ++nt) {
      f32x4 a = {};
      f16x8 b0 = *(const f16x8*)&Ks[(nt * 16 + l16) * 64 + quad * 8];
      f16x8 b1 = *(const f16x8*)&Ks[(nt * 16 + l16) * 64 + 32 + quad * 8];
      a = __builtin_amdgcn_mfma_f32_16x16x32_f16(aq0, b0, a, 0, 0, 0);
      a = __builtin_amdgcn_mfma_f32_16x16x32_f16(aq1, b1, a, 0, 0, 0);
      s[nt] = a;
    }

    // ---- online softmax (scale 1/8 folded into exp)
    float alpha[4], rs[4];
#pragma unroll
    for (int g = 0; g < 4; ++g) {
      float v = fmaxf(fmaxf(s[0][g], s[1][g]), fmaxf(s[2][g], s[3][g]));
      v = fmaxf(v, __shfl_xor(v, 1));
      v = fmaxf(v, __shfl_xor(v, 2));
      v = fmaxf(v, __shfl_xor(v, 4));
      v = fmaxf(v, __shfl_xor(v, 8));
      float mn = fmaxf(m_run[g], v);
      alpha[g] = __expf((m_run[g] - mn) * 0.125f);
      m_run[g] = mn;
      rs[g] = 0.f;
    }
#pragma unroll
    for (int nt = 0; nt < 4; ++nt)
#pragma unroll
      for (int g = 0; g < 4; ++g) {
        float p = __expf((s[nt][g] - m_run[g]) * 0.125f);
        rs[g] += p;
        Ps[wid][(quad * 4 + g) * 72 + nt * 16 + l16] = f2h(p);  // C-layout -> LDS
      }
#pragma unroll
    for (int g = 0; g < 4; ++g) {
      float v = rs[g];
      v += __shfl_xor(v, 1);
      v += __shfl_xor(v, 2);
      v += __shfl_xor(v, 4);
      v += __shfl_xor(v, 8);
      l_run[g] = l_run[g] * alpha[g] + v;
#pragma unroll
      for (int i = 0; i < 4; ++i) o4[g][i] *= alpha[g];
    }

    // ---- O += P @ V : pure VALU from Ps and plain Vs (bisection)
    for (int n = 0; n < 64; ++n) {
      f16x4 vv = *(const f16x4*)&Vs[n * 72 + l16 * 4];
      float vf[4];
#pragma unroll
      for (int i = 0; i < 4; ++i) vf[i] = (float)vv[i];
#pragma unroll
      for (int g = 0; g < 4; ++g) {
        float p = h2f(Ps[wid][(quad * 4 + g) * 72 + n]);
#pragma unroll
        for (int i = 0; i < 4; ++i) o4[g][i] += p * vf[i];
      }
    }
  }

  // ---- epilogue: normalize, store fp16 (cols l16*4+i)
#pragma unroll
  for (int g = 0; g < 4; ++g) {
    float rl = 1.f / l_run[g];
    int row = qb * 64 + wid * 16 + quad * 4 + g;
#pragma unroll
    for (int i = 0; i < 4; ++i)
      Ob[row * DMODEL + hc + l16 * 4 + i] = f2h(o4[g][i] * rl);
  }
}

// ---------------------------------------------------------------------------
extern "C" void kernel_launch(void* const* d_in, const int* in_sizes, int n_in,
                              void* d_out, int out_size, void* d_ws, size_t ws_size,
                              hipStream_t stream) {
  const float* q  = (const float*)d_in[0];
  const float* k  = (const float*)d_in[1];
  const float* v  = (const float*)d_in[2];
  const float* Wq = (const float*)d_in[3];
  const float* Wk = (const float*)d_in[4];
  const float* Wv = (const float*)d_in[5];
  const float* Wo = (const float*)d_in[6];
  const float* bo = (const float*)d_in[7];

  unsigned short* ws  = (unsigned short*)d_ws;
  unsigned short* Wqt = ws;                  // 512*512 fp16 each
  unsigned short* Wkt = Wqt + 262144;
  unsigned short* Wvt = Wkt + 262144;
  unsigned short* Wot = Wvt + 262144;
  unsigned short* Qb  = Wot + 262144;        // 4096*512 fp16 each
  unsigned short* Kb  = Qb + 2097152;
  unsigned short* Vb  = Kb + 2097152;
  unsigned short* Ab  = Vb + 2097152;        // attention output
  unsigned short* O1  = Kb;                  // fc1 output aliases Kb (dead after attn)
  // peak ws use: 18.97 MB (== round-2 proven high-water)

  wtrans_kernel<<<dim3(8, 8, 4), 256, 0, stream>>>(Wq, Wk, Wv, Wo, Wqt, Wkt, Wvt, Wot);

  gemm_kernel<<<dim3(64, 8), 256, 0, stream>>>(q, Wqt, Qb, nullptr, 1, 0);
  gemm_kernel<<<dim3(64, 8), 256, 0, stream>>>(k, Wkt, Kb, nullptr, 1, 0);
  gemm_kernel<<<dim3(64, 8), 256, 0, stream>>>(v, Wvt, Vb, nullptr, 1, 0);

  attn_kernel<<<dim3(64, 8), 256, 0, stream>>>(Qb, Kb, Vb, Ab);

  gemm_kernel<<<dim3(64, 8), 256, 0, stream>>>(Ab, Wot, O1, bo, 0, 0);
  gemm_kernel<<<dim3(64, 8), 256, 0, stream>>>(O1, Wot, d_out, bo, 0, 1);
}

// Round 9
// 330.716 us; speedup vs baseline: 25.2904x; 1.7510x over previous
//
#include <hip/hip_runtime.h>

#define S_LEN  4096
#define DMODEL 512
#define NH     8
#define HD     64

typedef _Float16 f16x8 __attribute__((ext_vector_type(8)));
typedef float    f32x4 __attribute__((ext_vector_type(4)));

static __device__ __forceinline__ unsigned short f2h(float x) {
  return __builtin_bit_cast(unsigned short, (_Float16)x);
}

// ---------------------------------------------------------------------------
// Weight transpose + fp32->fp16 convert: Wt[n][k] = (fp16) W[k][n]
// grid (8,8,4) block 256   [proven round 2/4]
// ---------------------------------------------------------------------------
__global__ __launch_bounds__(256) void wtrans_kernel(
    const float* __restrict__ w0, const float* __restrict__ w1,
    const float* __restrict__ w2, const float* __restrict__ w3,
    unsigned short* __restrict__ o0, unsigned short* __restrict__ o1,
    unsigned short* __restrict__ o2, unsigned short* __restrict__ o3)
{
  __shared__ unsigned short T[64 * 72];   // T[n_local][k_local], pad 72
  const float* W; unsigned short* O;
  switch (blockIdx.z) {
    case 0:  W = w0; O = o0; break;
    case 1:  W = w1; O = o1; break;
    case 2:  W = w2; O = o2; break;
    default: W = w3; O = o3; break;
  }
  const int tid = threadIdx.x;
  const int k0 = blockIdx.x * 64, n0 = blockIdx.y * 64;
  const int c4 = (tid & 15) * 4;
#pragma unroll
  for (int rp = 0; rp < 4; ++rp) {
    int r = rp * 16 + (tid >> 4);
    float4 x = *(const float4*)(W + (k0 + r) * DMODEL + n0 + c4);
    T[(c4 + 0) * 72 + r] = f2h(x.x);
    T[(c4 + 1) * 72 + r] = f2h(x.y);
    T[(c4 + 2) * 72 + r] = f2h(x.z);
    T[(c4 + 3) * 72 + r] = f2h(x.w);
  }
  __syncthreads();
#pragma unroll
  for (int it = 0; it < 2; ++it) {
    int i = tid + it * 256;
    int nl = i >> 3, c = i & 7;
    *(f16x8*)&O[(n0 + nl) * DMODEL + k0 + c * 8] = *(const f16x8*)&T[nl * 72 + c * 8];
  }
}

// ---------------------------------------------------------------------------
// GEMM: C[4096][512] = A[4096][512] @ Bt[512][512]^T (+bias)
// [byte-identical to round-2-proven version]
// ---------------------------------------------------------------------------
__global__ __launch_bounds__(256) void gemm_kernel(
    const void* __restrict__ Av, const unsigned short* __restrict__ Bt,
    void* __restrict__ Cv, const float* __restrict__ bias,
    int a_fp32, int c_fp32)
{
  constexpr int K = DMODEL, N = DMODEL;
  __shared__ unsigned short As[64 * 32];
  __shared__ unsigned short Bs[64 * 32];
  const int tid  = threadIdx.x;
  const int lane = tid & 63;
  const int wid  = tid >> 6;
  const int quad = lane >> 4, l16 = lane & 15;
  const int m0 = blockIdx.x * 64, n0 = blockIdx.y * 64;
  const int wm = (wid >> 1) * 32, wn = (wid & 1) * 32;
  const int r  = tid >> 2, ck = (tid & 3) * 8;   // staging: row, k-offset
  f32x4 acc[2][2] = {};

  for (int k0 = 0; k0 < K; k0 += 32) {
    __syncthreads();
    if (a_fp32) {
      const float* p = (const float*)Av + (m0 + r) * K + k0 + ck;
      float4 x = *(const float4*)p;
      float4 y = *(const float4*)(p + 4);
      f16x8 av;
      av[0] = (_Float16)x.x; av[1] = (_Float16)x.y;
      av[2] = (_Float16)x.z; av[3] = (_Float16)x.w;
      av[4] = (_Float16)y.x; av[5] = (_Float16)y.y;
      av[6] = (_Float16)y.z; av[7] = (_Float16)y.w;
      *(f16x8*)&As[r * 32 + ck] = av;
    } else {
      *(f16x8*)&As[r * 32 + ck] =
          *(const f16x8*)((const unsigned short*)Av + (m0 + r) * K + k0 + ck);
    }
    *(f16x8*)&Bs[r * 32 + ck] = *(const f16x8*)(Bt + (n0 + r) * K + k0 + ck);
    __syncthreads();

    f16x8 a0 = *(const f16x8*)&As[(wm + l16) * 32 + quad * 8];
    f16x8 a1 = *(const f16x8*)&As[(wm + 16 + l16) * 32 + quad * 8];
    f16x8 b0 = *(const f16x8*)&Bs[(wn + l16) * 32 + quad * 8];
    f16x8 b1 = *(const f16x8*)&Bs[(wn + 16 + l16) * 32 + quad * 8];
    acc[0][0] = __builtin_amdgcn_mfma_f32_16x16x32_f16(a0, b0, acc[0][0], 0, 0, 0);
    acc[0][1] = __builtin_amdgcn_mfma_f32_16x16x32_f16(a0, b1, acc[0][1], 0, 0, 0);
    acc[1][0] = __builtin_amdgcn_mfma_f32_16x16x32_f16(a1, b0, acc[1][0], 0, 0, 0);
    acc[1][1] = __builtin_amdgcn_mfma_f32_16x16x32_f16(a1, b1, acc[1][1], 0, 0, 0);
  }

#pragma unroll
  for (int mt = 0; mt < 2; ++mt)
#pragma unroll
    for (int nt = 0; nt < 2; ++nt) {
      int col = n0 + wn + nt * 16 + l16;
      float bv = bias ? bias[col] : 0.f;
#pragma unroll
      for (int g = 0; g < 4; ++g) {
        int row = m0 + wm + mt * 16 + quad * 4 + g;   // C/D: row = quad*4+reg
        float val = acc[mt][nt][g] + bv;
        if (c_fp32) ((float*)Cv)[row * N + col] = val;
        else        ((unsigned short*)Cv)[row * N + col] = f2h(val);
      }
    }
}

// ---------------------------------------------------------------------------
// Round-9 attention = round-4 PASSING kernel with ONLY the PV block and
// epilogue changed: PV via MFMA whose A (P) and B (V^T) fragments are
// assembled from SCALAR reads of the round-4-proven Ps and Vs arrays.
// No vtrans, no V^T buffers, no vector LDS reads of Ps/Vs.
// grid (64, 8), block 256.
// ---------------------------------------------------------------------------
__global__ __launch_bounds__(256) void attn_kernel(
    const unsigned short* __restrict__ Qb, const unsigned short* __restrict__ Kb,
    const unsigned short* __restrict__ Vb, unsigned short* __restrict__ Ob)
{
  __shared__ unsigned short Ks[64 * 64];   // K[n][k]          [round-4 proven]
  __shared__ unsigned short Vs[64 * 72];   // V[n][d], pad 72  [round-4 proven]
  __shared__ unsigned short Ps[4][16 * 72];// per-wave P       [round-4 proven]

  const int tid  = threadIdx.x;
  const int lane = tid & 63;
  const int wid  = tid >> 6;
  const int quad = lane >> 4, l16 = lane & 15;
  const int qb = blockIdx.x, h = blockIdx.y;
  const int hc = h * HD;

  // Persistent Q A-fragments [round-4 proven]
  const int qrow = qb * 64 + wid * 16 + l16;
  const f16x8 aq0 = *(const f16x8*)(Qb + qrow * DMODEL + hc + quad * 8);
  const f16x8 aq1 = *(const f16x8*)(Qb + qrow * DMODEL + hc + 32 + quad * 8);

  f32x4 o[4] = {};
  float m_run[4], l_run[4];
#pragma unroll
  for (int i = 0; i < 4; ++i) { m_run[i] = -1e30f; l_run[i] = 0.f; }

  for (int kb = 0; kb < S_LEN / 64; ++kb) {
    __syncthreads();
    // ---- stage K[n][k] and V[n][d] plain [round-4 proven verbatim]
    {
      int i = tid;
#pragma unroll
      for (int it = 0; it < 2; ++it, i += 256) {
        int n = i >> 3, c = i & 7;
        *(f16x8*)&Ks[n * 64 + c * 8] =
            *(const f16x8*)(Kb + (kb * 64 + n) * DMODEL + hc + c * 8);
        *(f16x8*)&Vs[n * 72 + c * 8] =
            *(const f16x8*)(Vb + (kb * 64 + n) * DMODEL + hc + c * 8);
      }
    }
    __syncthreads();

    // ---- S = Q K^T [round-4 proven verbatim]
    f32x4 s[4];
#pragma unroll
    for (int nt = 0; nt < 4; ++nt) {
      f32x4 a = {};
      f16x8 b0 = *(const f16x8*)&Ks[(nt * 16 + l16) * 64 + quad * 8];
      f16x8 b1 = *(const f16x8*)&Ks[(nt * 16 + l16) * 64 + 32 + quad * 8];
      a = __builtin_amdgcn_mfma_f32_16x16x32_f16(aq0, b0, a, 0, 0, 0);
      a = __builtin_amdgcn_mfma_f32_16x16x32_f16(aq1, b1, a, 0, 0, 0);
      s[nt] = a;
    }

    // ---- online softmax [round-4 proven verbatim]
    float alpha[4], rs[4];
#pragma unroll
    for (int g = 0; g < 4; ++g) {
      float v = fmaxf(fmaxf(s[0][g], s[1][g]), fmaxf(s[2][g], s[3][g]));
      v = fmaxf(v, __shfl_xor(v, 1));
      v = fmaxf(v, __shfl_xor(v, 2));
      v = fmaxf(v, __shfl_xor(v, 4));
      v = fmaxf(v, __shfl_xor(v, 8));
      float mn = fmaxf(m_run[g], v);
      alpha[g] = __expf((m_run[g] - mn) * 0.125f);
      m_run[g] = mn;
      rs[g] = 0.f;
    }
#pragma unroll
    for (int nt = 0; nt < 4; ++nt)
#pragma unroll
      for (int g = 0; g < 4; ++g) {
        float p = __expf((s[nt][g] - m_run[g]) * 0.125f);
        rs[g] += p;
        Ps[wid][(quad * 4 + g) * 72 + nt * 16 + l16] = f2h(p);
      }
#pragma unroll
    for (int g = 0; g < 4; ++g) {
      float v = rs[g];
      v += __shfl_xor(v, 1);
      v += __shfl_xor(v, 2);
      v += __shfl_xor(v, 4);
      v += __shfl_xor(v, 8);
      l_run[g] = l_run[g] * alpha[g] + v;
#pragma unroll
      for (int t = 0; t < 4; ++t) o[t][g] *= alpha[g];
    }

    __syncthreads();

    // ---- O += P @ V via MFMA; operands assembled from SCALAR LDS reads of
    // the round-4-proven Ps (P[row][key]) and Vs (V[key][d]) arrays.
    f16x8 pf0, pf1;
#pragma unroll
    for (int j = 0; j < 8; ++j) {
      pf0[j] = __builtin_bit_cast(_Float16, Ps[wid][l16 * 72 + quad * 8 + j]);
      pf1[j] = __builtin_bit_cast(_Float16, Ps[wid][l16 * 72 + 32 + quad * 8 + j]);
    }
#pragma unroll
    for (int t = 0; t < 4; ++t) {
      f16x8 vf0, vf1;
#pragma unroll
      for (int j = 0; j < 8; ++j) {
        vf0[j] = __builtin_bit_cast(_Float16, Vs[(quad * 8 + j) * 72 + t * 16 + l16]);
        vf1[j] = __builtin_bit_cast(_Float16, Vs[(32 + quad * 8 + j) * 72 + t * 16 + l16]);
      }
      o[t] = __builtin_amdgcn_mfma_f32_16x16x32_f16(pf0, vf0, o[t], 0, 0, 0);
      o[t] = __builtin_amdgcn_mfma_f32_16x16x32_f16(pf1, vf1, o[t], 0, 0, 0);
    }
  }

  // ---- epilogue: GEMM-proven C-layout store map
#pragma unroll
  for (int g = 0; g < 4; ++g) {
    float rl = 1.f / l_run[g];
    int row = qb * 64 + wid * 16 + quad * 4 + g;
#pragma unroll
    for (int t = 0; t < 4; ++t)
      Ob[row * DMODEL + hc + t * 16 + l16] = f2h(o[t][g] * rl);
  }
}

// ---------------------------------------------------------------------------
extern "C" void kernel_launch(void* const* d_in, const int* in_sizes, int n_in,
                              void* d_out, int out_size, void* d_ws, size_t ws_size,
                              hipStream_t stream) {
  const float* q  = (const float*)d_in[0];
  const float* k  = (const float*)d_in[1];
  const float* v  = (const float*)d_in[2];
  const float* Wq = (const float*)d_in[3];
  const float* Wk = (const float*)d_in[4];
  const float* Wv = (const float*)d_in[5];
  const float* Wo = (const float*)d_in[6];
  const float* bo = (const float*)d_in[7];

  unsigned short* ws  = (unsigned short*)d_ws;
  unsigned short* Wqt = ws;                  // 512*512 fp16 each
  unsigned short* Wkt = Wqt + 262144;
  unsigned short* Wvt = Wkt + 262144;
  unsigned short* Wot = Wvt + 262144;
  unsigned short* Qb  = Wot + 262144;        // 4096*512 fp16 each
  unsigned short* Kb  = Qb + 2097152;
  unsigned short* Vb  = Kb + 2097152;
  unsigned short* Ab  = Vb + 2097152;        // attention output
  unsigned short* O1  = Kb;                  // fc1 output aliases dead Kb
  // layout byte-identical to round-2/4 proven arrangement (18.97 MB)

  wtrans_kernel<<<dim3(8, 8, 4), 256, 0, stream>>>(Wq, Wk, Wv, Wo, Wqt, Wkt, Wvt, Wot);

  gemm_kernel<<<dim3(64, 8), 256, 0, stream>>>(q, Wqt, Qb, nullptr, 1, 0);
  gemm_kernel<<<dim3(64, 8), 256, 0, stream>>>(k, Wkt, Kb, nullptr, 1, 0);
  gemm_kernel<<<dim3(64, 8), 256, 0, stream>>>(v, Wvt, Vb, nullptr, 1, 0);

  attn_kernel<<<dim3(64, 8), 256, 0, stream>>>(Qb, Kb, Vb, Ab);

  gemm_kernel<<<dim3(64, 8), 256, 0, stream>>>(Ab, Wot, O1, bo, 0, 0);
  gemm_kernel<<<dim3(64, 8), 256, 0, stream>>>(O1, Wot, d_out, bo, 0, 1);
}

// Round 10
// 301.832 us; speedup vs baseline: 27.7107x; 1.0957x over previous
//
#include <hip/hip_runtime.h>

#define S_LEN  4096
#define DMODEL 512
#define NH     8
#define HD     64

typedef _Float16 f16x8 __attribute__((ext_vector_type(8)));
typedef float    f32x4 __attribute__((ext_vector_type(4)));

static __device__ __forceinline__ unsigned short f2h(float x) {
  return __builtin_bit_cast(unsigned short, (_Float16)x);
}

// ---------------------------------------------------------------------------
// Weight transpose + fp32->fp16 convert: Wt[n][k] = (fp16) W[k][n]
// grid (8,8,4) block 256   [proven]
// ---------------------------------------------------------------------------
__global__ __launch_bounds__(256) void wtrans_kernel(
    const float* __restrict__ w0, const float* __restrict__ w1,
    const float* __restrict__ w2, const float* __restrict__ w3,
    unsigned short* __restrict__ o0, unsigned short* __restrict__ o1,
    unsigned short* __restrict__ o2, unsigned short* __restrict__ o3)
{
  __shared__ unsigned short T[64 * 72];   // T[n_local][k_local], pad 72
  const float* W; unsigned short* O;
  switch (blockIdx.z) {
    case 0:  W = w0; O = o0; break;
    case 1:  W = w1; O = o1; break;
    case 2:  W = w2; O = o2; break;
    default: W = w3; O = o3; break;
  }
  const int tid = threadIdx.x;
  const int k0 = blockIdx.x * 64, n0 = blockIdx.y * 64;
  const int c4 = (tid & 15) * 4;
#pragma unroll
  for (int rp = 0; rp < 4; ++rp) {
    int r = rp * 16 + (tid >> 4);
    float4 x = *(const float4*)(W + (k0 + r) * DMODEL + n0 + c4);
    T[(c4 + 0) * 72 + r] = f2h(x.x);
    T[(c4 + 1) * 72 + r] = f2h(x.y);
    T[(c4 + 2) * 72 + r] = f2h(x.z);
    T[(c4 + 3) * 72 + r] = f2h(x.w);
  }
  __syncthreads();
#pragma unroll
  for (int it = 0; it < 2; ++it) {
    int i = tid + it * 256;
    int nl = i >> 3, c = i & 7;
    *(f16x8*)&O[(n0 + nl) * DMODEL + k0 + c * 8] = *(const f16x8*)&T[nl * 72 + c * 8];
  }
}

// ---------------------------------------------------------------------------
// GEMM (multi-op): blockIdx.z selects (A,Bt,C) triple. Body identical to the
// round-2/4/9 proven kernel. grid (64,8,nz) block 256.
// ---------------------------------------------------------------------------
__global__ __launch_bounds__(256) void gemm_kernel(
    const void* __restrict__ A0, const void* __restrict__ A1, const void* __restrict__ A2,
    const unsigned short* __restrict__ B0, const unsigned short* __restrict__ B1,
    const unsigned short* __restrict__ B2,
    void* __restrict__ C0, void* __restrict__ C1, void* __restrict__ C2,
    const float* __restrict__ bias, int a_fp32, int c_fp32)
{
  constexpr int K = DMODEL, N = DMODEL;
  __shared__ unsigned short As[64 * 32];
  __shared__ unsigned short Bs[64 * 32];
  const void* Av; const unsigned short* Bt; void* Cv;
  switch (blockIdx.z) {
    case 0:  Av = A0; Bt = B0; Cv = C0; break;
    case 1:  Av = A1; Bt = B1; Cv = C1; break;
    default: Av = A2; Bt = B2; Cv = C2; break;
  }
  const int tid  = threadIdx.x;
  const int lane = tid & 63;
  const int wid  = tid >> 6;
  const int quad = lane >> 4, l16 = lane & 15;
  const int m0 = blockIdx.x * 64, n0 = blockIdx.y * 64;
  const int wm = (wid >> 1) * 32, wn = (wid & 1) * 32;
  const int r  = tid >> 2, ck = (tid & 3) * 8;   // staging: row, k-offset
  f32x4 acc[2][2] = {};

  for (int k0 = 0; k0 < K; k0 += 32) {
    __syncthreads();
    if (a_fp32) {
      const float* p = (const float*)Av + (m0 + r) * K + k0 + ck;
      float4 x = *(const float4*)p;
      float4 y = *(const float4*)(p + 4);
      f16x8 av;
      av[0] = (_Float16)x.x; av[1] = (_Float16)x.y;
      av[2] = (_Float16)x.z; av[3] = (_Float16)x.w;
      av[4] = (_Float16)y.x; av[5] = (_Float16)y.y;
      av[6] = (_Float16)y.z; av[7] = (_Float16)y.w;
      *(f16x8*)&As[r * 32 + ck] = av;
    } else {
      *(f16x8*)&As[r * 32 + ck] =
          *(const f16x8*)((const unsigned short*)Av + (m0 + r) * K + k0 + ck);
    }
    *(f16x8*)&Bs[r * 32 + ck] = *(const f16x8*)(Bt + (n0 + r) * K + k0 + ck);
    __syncthreads();

    f16x8 a0 = *(const f16x8*)&As[(wm + l16) * 32 + quad * 8];
    f16x8 a1 = *(const f16x8*)&As[(wm + 16 + l16) * 32 + quad * 8];
    f16x8 b0 = *(const f16x8*)&Bs[(wn + l16) * 32 + quad * 8];
    f16x8 b1 = *(const f16x8*)&Bs[(wn + 16 + l16) * 32 + quad * 8];
    acc[0][0] = __builtin_amdgcn_mfma_f32_16x16x32_f16(a0, b0, acc[0][0], 0, 0, 0);
    acc[0][1] = __builtin_amdgcn_mfma_f32_16x16x32_f16(a0, b1, acc[0][1], 0, 0, 0);
    acc[1][0] = __builtin_amdgcn_mfma_f32_16x16x32_f16(a1, b0, acc[1][0], 0, 0, 0);
    acc[1][1] = __builtin_amdgcn_mfma_f32_16x16x32_f16(a1, b1, acc[1][1], 0, 0, 0);
  }

#pragma unroll
  for (int mt = 0; mt < 2; ++mt)
#pragma unroll
    for (int nt = 0; nt < 2; ++nt) {
      int col = n0 + wn + nt * 16 + l16;
      float bv = bias ? bias[col] : 0.f;
#pragma unroll
      for (int g = 0; g < 4; ++g) {
        int row = m0 + wm + mt * 16 + quad * 4 + g;   // C/D: row = quad*4+reg
        float val = acc[mt][nt][g] + bv;
        if (c_fp32) ((float*)Cv)[row * N + col] = val;
        else        ((unsigned short*)Cv)[row * N + col] = f2h(val);
      }
    }
}

// ---------------------------------------------------------------------------
// Split-K MFMA flash attention. Block = 512 threads = 8 waves:
// 4 q-subtiles (16 rows each) x 2 key-halves (2048 keys each). grid (64, 8).
// Access classes exactly as the round-9 PASSING kernel: f16x8 staging +
// vector Ks reads for QK^T, SCALAR Ps/Vs reads for PV operands.
// End-of-kernel merge of the two online-softmax states via LDS scratch.
// ---------------------------------------------------------------------------
__global__ __launch_bounds__(512) void attn_kernel(
    const unsigned short* __restrict__ Qb, const unsigned short* __restrict__ Kb,
    const unsigned short* __restrict__ Vb, unsigned short* __restrict__ Ob)
{
  __shared__ unsigned short Ks[2][64 * 64];   // K[n][k] per half   16 KB
  __shared__ unsigned short Vs[2][64 * 72];   // V[n][d] per half   18.4 KB
  __shared__ unsigned short Ps[8][16 * 72];   // per-wave P         18.4 KB
  __shared__ _Float16 Osc[4][64][16];         // merge scratch o     8 KB
  __shared__ float    Msc[4][64][4];          // merge scratch m     4 KB
  __shared__ float    Lsc[4][64][4];          // merge scratch l     4 KB

  const int tid  = threadIdx.x;
  const int lane = tid & 63;
  const int wid  = tid >> 6;        // 0..7
  const int qsub = wid & 3;         // q-subtile
  const int kh   = wid >> 2;        // key half
  const int quad = lane >> 4, l16 = lane & 15;
  const int qb = blockIdx.x, h = blockIdx.y;
  const int hc = h * HD;

  // Persistent Q A-fragments [proven]
  const int qrow = qb * 64 + qsub * 16 + l16;
  const f16x8 aq0 = *(const f16x8*)(Qb + qrow * DMODEL + hc + quad * 8);
  const f16x8 aq1 = *(const f16x8*)(Qb + qrow * DMODEL + hc + 32 + quad * 8);

  f32x4 o[4] = {};
  float m_run[4], l_run[4];
#pragma unroll
  for (int i = 0; i < 4; ++i) { m_run[i] = -1e30f; l_run[i] = 0.f; }

  for (int kbi = 0; kbi < 32; ++kbi) {
    __syncthreads();
    // ---- stage both key-halves' current 64-key chunk (K + V), 512 threads
#pragma unroll
    for (int it = 0; it < 2; ++it) {
      int s = it * 512 + tid;                 // 0..1023
      int khs = s >> 9, n = (s >> 3) & 63, c = s & 7;
      int key = khs * 2048 + kbi * 64 + n;
      *(f16x8*)&Ks[khs][n * 64 + c * 8] =
          *(const f16x8*)(Kb + key * DMODEL + hc + c * 8);
      *(f16x8*)&Vs[khs][n * 72 + c * 8] =
          *(const f16x8*)(Vb + key * DMODEL + hc + c * 8);
    }
    __syncthreads();

    // ---- S = Q K^T from this wave's half [proven pattern]
    f32x4 s[4];
#pragma unroll
    for (int nt = 0; nt < 4; ++nt) {
      f32x4 a = {};
      f16x8 b0 = *(const f16x8*)&Ks[kh][(nt * 16 + l16) * 64 + quad * 8];
      f16x8 b1 = *(const f16x8*)&Ks[kh][(nt * 16 + l16) * 64 + 32 + quad * 8];
      a = __builtin_amdgcn_mfma_f32_16x16x32_f16(aq0, b0, a, 0, 0, 0);
      a = __builtin_amdgcn_mfma_f32_16x16x32_f16(aq1, b1, a, 0, 0, 0);
      s[nt] = a;
    }

    // ---- online softmax (scale 1/8 folded into exp) [proven verbatim]
    float alpha[4], rs[4];
#pragma unroll
    for (int g = 0; g < 4; ++g) {
      float v = fmaxf(fmaxf(s[0][g], s[1][g]), fmaxf(s[2][g], s[3][g]));
      v = fmaxf(v, __shfl_xor(v, 1));
      v = fmaxf(v, __shfl_xor(v, 2));
      v = fmaxf(v, __shfl_xor(v, 4));
      v = fmaxf(v, __shfl_xor(v, 8));
      float mn = fmaxf(m_run[g], v);
      alpha[g] = __expf((m_run[g] - mn) * 0.125f);
      m_run[g] = mn;
      rs[g] = 0.f;
    }
#pragma unroll
    for (int nt = 0; nt < 4; ++nt)
#pragma unroll
      for (int g = 0; g < 4; ++g) {
        float p = __expf((s[nt][g] - m_run[g]) * 0.125f);
        rs[g] += p;
        Ps[wid][(quad * 4 + g) * 72 + nt * 16 + l16] = f2h(p);
      }
#pragma unroll
    for (int g = 0; g < 4; ++g) {
      float v = rs[g];
      v += __shfl_xor(v, 1);
      v += __shfl_xor(v, 2);
      v += __shfl_xor(v, 4);
      v += __shfl_xor(v, 8);
      l_run[g] = l_run[g] * alpha[g] + v;
#pragma unroll
      for (int t = 0; t < 4; ++t) o[t][g] *= alpha[g];
    }

    __syncthreads();

    // ---- O += P @ V : SCALAR operand assembly [round-9 proven class]
    f16x8 pf0, pf1;
#pragma unroll
    for (int j = 0; j < 8; ++j) {
      pf0[j] = __builtin_bit_cast(_Float16, Ps[wid][l16 * 72 + quad * 8 + j]);
      pf1[j] = __builtin_bit_cast(_Float16, Ps[wid][l16 * 72 + 32 + quad * 8 + j]);
    }
#pragma unroll
    for (int t = 0; t < 4; ++t) {
      f16x8 vf0, vf1;
#pragma unroll
      for (int j = 0; j < 8; ++j) {
        vf0[j] = __builtin_bit_cast(_Float16, Vs[kh][(quad * 8 + j) * 72 + t * 16 + l16]);
        vf1[j] = __builtin_bit_cast(_Float16, Vs[kh][(32 + quad * 8 + j) * 72 + t * 16 + l16]);
      }
      o[t] = __builtin_amdgcn_mfma_f32_16x16x32_f16(pf0, vf0, o[t], 0, 0, 0);
      o[t] = __builtin_amdgcn_mfma_f32_16x16x32_f16(pf1, vf1, o[t], 0, 0, 0);
    }
  }

  // ---- merge the two key-half states per q-subtile, then store
  __syncthreads();
  if (kh == 1) {
#pragma unroll
    for (int g = 0; g < 4; ++g) {
      Msc[qsub][lane][g] = m_run[g];
      Lsc[qsub][lane][g] = l_run[g];
#pragma unroll
      for (int t = 0; t < 4; ++t)
        Osc[qsub][lane][t * 4 + g] = (_Float16)o[t][g];
    }
  }
  __syncthreads();
  if (kh == 0) {
#pragma unroll
    for (int g = 0; g < 4; ++g) {
      float m1 = Msc[qsub][lane][g];
      float l1 = Lsc[qsub][lane][g];
      float m  = fmaxf(m_run[g], m1);
      float a0 = __expf((m_run[g] - m) * 0.125f);
      float a1 = __expf((m1 - m) * 0.125f);
      float rl = 1.f / (l_run[g] * a0 + l1 * a1);
      int row = qb * 64 + qsub * 16 + quad * 4 + g;
#pragma unroll
      for (int t = 0; t < 4; ++t) {
        float om = o[t][g] * a0 + (float)Osc[qsub][lane][t * 4 + g] * a1;
        Ob[row * DMODEL + hc + t * 16 + l16] = f2h(om * rl);
      }
    }
  }
}

// ---------------------------------------------------------------------------
extern "C" void kernel_launch(void* const* d_in, const int* in_sizes, int n_in,
                              void* d_out, int out_size, void* d_ws, size_t ws_size,
                              hipStream_t stream) {
  const float* q  = (const float*)d_in[0];
  const float* k  = (const float*)d_in[1];
  const float* v  = (const float*)d_in[2];
  const float* Wq = (const float*)d_in[3];
  const float* Wk = (const float*)d_in[4];
  const float* Wv = (const float*)d_in[5];
  const float* Wo = (const float*)d_in[6];
  const float* bo = (const float*)d_in[7];

  unsigned short* ws  = (unsigned short*)d_ws;
  unsigned short* Wqt = ws;                  // 512*512 fp16 each
  unsigned short* Wkt = Wqt + 262144;
  unsigned short* Wvt = Wkt + 262144;
  unsigned short* Wot = Wvt + 262144;
  unsigned short* Qb  = Wot + 262144;        // 4096*512 fp16 each
  unsigned short* Kb  = Qb + 2097152;
  unsigned short* Vb  = Kb + 2097152;
  unsigned short* Ab  = Vb + 2097152;        // attention output
  unsigned short* O1  = Kb;                  // fc1 output aliases dead Kb
  // layout byte-identical to round-2/4/9 proven arrangement (18.97 MB)

  wtrans_kernel<<<dim3(8, 8, 4), 256, 0, stream>>>(Wq, Wk, Wv, Wo, Wqt, Wkt, Wvt, Wot);

  // Q/K/V projections fused into one launch (z selects the op)
  gemm_kernel<<<dim3(64, 8, 3), 256, 0, stream>>>(
      q, k, v, Wqt, Wkt, Wvt, Qb, Kb, Vb, nullptr, 1, 0);

  attn_kernel<<<dim3(64, 8), 512, 0, stream>>>(Qb, Kb, Vb, Ab);

  gemm_kernel<<<dim3(64, 8, 1), 256, 0, stream>>>(
      Ab, Ab, Ab, Wot, Wot, Wot, O1, O1, O1, bo, 0, 0);
  gemm_kernel<<<dim3(64, 8, 1), 256, 0, stream>>>(
      O1, O1, O1, Wot, Wot, Wot, d_out, d_out, d_out, bo, 0, 1);
}

// Round 11
// 229.711 us; speedup vs baseline: 36.4109x; 1.3140x over previous
//
#include <hip/hip_runtime.h>

#define S_LEN  4096
#define DMODEL 512
#define NH     8
#define HD     64

typedef _Float16 f16x8 __attribute__((ext_vector_type(8)));
typedef _Float16 f16x4 __attribute__((ext_vector_type(4)));
typedef float    f32x4 __attribute__((ext_vector_type(4)));

static __device__ __forceinline__ unsigned short f2h(float x) {
  return __builtin_bit_cast(unsigned short, (_Float16)x);
}

// ---------------------------------------------------------------------------
// Weight transpose + fp32->fp16 convert: Wt[n][k] = (fp16) W[k][n]
// grid (8,8,4) block 256   [proven]
// ---------------------------------------------------------------------------
__global__ __launch_bounds__(256) void wtrans_kernel(
    const float* __restrict__ w0, const float* __restrict__ w1,
    const float* __restrict__ w2, const float* __restrict__ w3,
    unsigned short* __restrict__ o0, unsigned short* __restrict__ o1,
    unsigned short* __restrict__ o2, unsigned short* __restrict__ o3)
{
  __shared__ unsigned short T[64 * 72];   // T[n_local][k_local], pad 72
  const float* W; unsigned short* O;
  switch (blockIdx.z) {
    case 0:  W = w0; O = o0; break;
    case 1:  W = w1; O = o1; break;
    case 2:  W = w2; O = o2; break;
    default: W = w3; O = o3; break;
  }
  const int tid = threadIdx.x;
  const int k0 = blockIdx.x * 64, n0 = blockIdx.y * 64;
  const int c4 = (tid & 15) * 4;
#pragma unroll
  for (int rp = 0; rp < 4; ++rp) {
    int r = rp * 16 + (tid >> 4);
    float4 x = *(const float4*)(W + (k0 + r) * DMODEL + n0 + c4);
    T[(c4 + 0) * 72 + r] = f2h(x.x);
    T[(c4 + 1) * 72 + r] = f2h(x.y);
    T[(c4 + 2) * 72 + r] = f2h(x.z);
    T[(c4 + 3) * 72 + r] = f2h(x.w);
  }
  __syncthreads();
#pragma unroll
  for (int it = 0; it < 2; ++it) {
    int i = tid + it * 256;
    int nl = i >> 3, c = i & 7;
    *(f16x8*)&O[(n0 + nl) * DMODEL + k0 + c * 8] = *(const f16x8*)&T[nl * 72 + c * 8];
  }
}

// ---------------------------------------------------------------------------
// GEMM (multi-op): blockIdx.z selects (A,Bt,C) triple. [proven verbatim]
// grid (64,8,nz) block 256.
// ---------------------------------------------------------------------------
__global__ __launch_bounds__(256) void gemm_kernel(
    const void* __restrict__ A0, const void* __restrict__ A1, const void* __restrict__ A2,
    const unsigned short* __restrict__ B0, const unsigned short* __restrict__ B1,
    const unsigned short* __restrict__ B2,
    void* __restrict__ C0, void* __restrict__ C1, void* __restrict__ C2,
    const float* __restrict__ bias, int a_fp32, int c_fp32)
{
  constexpr int K = DMODEL, N = DMODEL;
  __shared__ unsigned short As[64 * 32];
  __shared__ unsigned short Bs[64 * 32];
  const void* Av; const unsigned short* Bt; void* Cv;
  switch (blockIdx.z) {
    case 0:  Av = A0; Bt = B0; Cv = C0; break;
    case 1:  Av = A1; Bt = B1; Cv = C1; break;
    default: Av = A2; Bt = B2; Cv = C2; break;
  }
  const int tid  = threadIdx.x;
  const int lane = tid & 63;
  const int wid  = tid >> 6;
  const int quad = lane >> 4, l16 = lane & 15;
  const int m0 = blockIdx.x * 64, n0 = blockIdx.y * 64;
  const int wm = (wid >> 1) * 32, wn = (wid & 1) * 32;
  const int r  = tid >> 2, ck = (tid & 3) * 8;   // staging: row, k-offset
  f32x4 acc[2][2] = {};

  for (int k0 = 0; k0 < K; k0 += 32) {
    __syncthreads();
    if (a_fp32) {
      const float* p = (const float*)Av + (m0 + r) * K + k0 + ck;
      float4 x = *(const float4*)p;
      float4 y = *(const float4*)(p + 4);
      f16x8 av;
      av[0] = (_Float16)x.x; av[1] = (_Float16)x.y;
      av[2] = (_Float16)x.z; av[3] = (_Float16)x.w;
      av[4] = (_Float16)y.x; av[5] = (_Float16)y.y;
      av[6] = (_Float16)y.z; av[7] = (_Float16)y.w;
      *(f16x8*)&As[r * 32 + ck] = av;
    } else {
      *(f16x8*)&As[r * 32 + ck] =
          *(const f16x8*)((const unsigned short*)Av + (m0 + r) * K + k0 + ck);
    }
    *(f16x8*)&Bs[r * 32 + ck] = *(const f16x8*)(Bt + (n0 + r) * K + k0 + ck);
    __syncthreads();

    f16x8 a0 = *(const f16x8*)&As[(wm + l16) * 32 + quad * 8];
    f16x8 a1 = *(const f16x8*)&As[(wm + 16 + l16) * 32 + quad * 8];
    f16x8 b0 = *(const f16x8*)&Bs[(wn + l16) * 32 + quad * 8];
    f16x8 b1 = *(const f16x8*)&Bs[(wn + 16 + l16) * 32 + quad * 8];
    acc[0][0] = __builtin_amdgcn_mfma_f32_16x16x32_f16(a0, b0, acc[0][0], 0, 0, 0);
    acc[0][1] = __builtin_amdgcn_mfma_f32_16x16x32_f16(a0, b1, acc[0][1], 0, 0, 0);
    acc[1][0] = __builtin_amdgcn_mfma_f32_16x16x32_f16(a1, b0, acc[1][0], 0, 0, 0);
    acc[1][1] = __builtin_amdgcn_mfma_f32_16x16x32_f16(a1, b1, acc[1][1], 0, 0, 0);
  }

#pragma unroll
  for (int mt = 0; mt < 2; ++mt)
#pragma unroll
    for (int nt = 0; nt < 2; ++nt) {
      int col = n0 + wn + nt * 16 + l16;
      float bv = bias ? bias[col] : 0.f;
#pragma unroll
      for (int g = 0; g < 4; ++g) {
        int row = m0 + wm + mt * 16 + quad * 4 + g;   // C/D: row = quad*4+reg
        float val = acc[mt][nt][g] + bv;
        if (c_fp32) ((float*)Cv)[row * N + col] = val;
        else        ((unsigned short*)Cv)[row * N + col] = f2h(val);
      }
    }
}

// ---------------------------------------------------------------------------
// Split-K MFMA flash attention, S^T formulation (P stays in registers).
// Block = 512 threads = 8 waves: 4 q-subtiles x 2 key-halves. grid (64, 8).
//  - QK^T: swapped operands (Ks frag = A, Q frag = B) -> S^T in C-layout,
//    which IS the A-layout of P for mfma_f32_16x16x16f16. No Ps LDS.
//  - Softmax: per-lane state for q = l16; cross-quad shfl_xor(16/32).
//  - PV: B-frags from SCALAR Vs reads (2-way-conflict-free pattern).
// ---------------------------------------------------------------------------
__global__ __launch_bounds__(512) void attn_kernel(
    const unsigned short* __restrict__ Qb, const unsigned short* __restrict__ Kb,
    const unsigned short* __restrict__ Vb, unsigned short* __restrict__ Ob)
{
  __shared__ unsigned short Ks[2][64 * 64];   // K[n][k] per half   16 KB
  __shared__ unsigned short Vs[2][64 * 72];   // V[n][d] per half   18.4 KB
  __shared__ _Float16 Osc[4][64][16];         // merge scratch o     8 KB
  __shared__ float    Msc[4][16];             // merge scratch m
  __shared__ float    Lsc[4][16];             // merge scratch l

  const int tid  = threadIdx.x;
  const int lane = tid & 63;
  const int wid  = tid >> 6;        // 0..7
  const int qsub = wid & 3;         // q-subtile
  const int kh   = wid >> 2;        // key half
  const int quad = lane >> 4, l16 = lane & 15;
  const int qb = blockIdx.x, h = blockIdx.y;
  const int hc = h * HD;

  // Persistent Q fragments, now used as the B operand (same data as before):
  // lane holds Q[q = l16][d = quad*8+j (+32)]
  const int qrow = qb * 64 + qsub * 16 + l16;
  const f16x8 bq0 = *(const f16x8*)(Qb + qrow * DMODEL + hc + quad * 8);
  const f16x8 bq1 = *(const f16x8*)(Qb + qrow * DMODEL + hc + 32 + quad * 8);

  // O accumulators: o[nt] holds O[q = quad*4+g][d = nt*16 + l16]
  f32x4 o[4] = {};
  // per-lane online-softmax state for q = l16
  float m_run = -1e30f, l_run = 0.f;

  for (int kbi = 0; kbi < 32; ++kbi) {
    __syncthreads();
    // ---- stage both key-halves' 64-key chunk (K + V) [proven verbatim]
#pragma unroll
    for (int it = 0; it < 2; ++it) {
      int s = it * 512 + tid;                 // 0..1023
      int khs = s >> 9, n = (s >> 3) & 63, c = s & 7;
      int key = khs * 2048 + kbi * 64 + n;
      *(f16x8*)&Ks[khs][n * 64 + c * 8] =
          *(const f16x8*)(Kb + key * DMODEL + hc + c * 8);
      *(f16x8*)&Vs[khs][n * 72 + c * 8] =
          *(const f16x8*)(Vb + key * DMODEL + hc + c * 8);
    }
    __syncthreads();

    // ---- S^T = K Q^T : sT[kt][g] = S^T[key = kt*16+quad*4+g][q = l16]
    f32x4 sT[4];
#pragma unroll
    for (int kt = 0; kt < 4; ++kt) {
      f32x4 a = {};
      f16x8 ak0 = *(const f16x8*)&Ks[kh][(kt * 16 + l16) * 64 + quad * 8];
      f16x8 ak1 = *(const f16x8*)&Ks[kh][(kt * 16 + l16) * 64 + 32 + quad * 8];
      a = __builtin_amdgcn_mfma_f32_16x16x32_f16(ak0, bq0, a, 0, 0, 0);
      a = __builtin_amdgcn_mfma_f32_16x16x32_f16(ak1, bq1, a, 0, 0, 0);
      sT[kt] = a;
    }

    // ---- online softmax for column q = l16 (scale 1/8 folded into exp)
    float vmax = -1e30f;
#pragma unroll
    for (int kt = 0; kt < 4; ++kt)
#pragma unroll
      for (int g = 0; g < 4; ++g) vmax = fmaxf(vmax, sT[kt][g]);
    vmax = fmaxf(vmax, __shfl_xor(vmax, 16));
    vmax = fmaxf(vmax, __shfl_xor(vmax, 32));
    const float mn = fmaxf(m_run, vmax);
    const float alpha = __expf((m_run - mn) * 0.125f);
    m_run = mn;

    float rs = 0.f;
    f16x4 pa[4];            // P A-fragments: P[q=l16][key=kt*16+quad*4+j]
#pragma unroll
    for (int kt = 0; kt < 4; ++kt)
#pragma unroll
      for (int g = 0; g < 4; ++g) {
        float p = __expf((sT[kt][g] - mn) * 0.125f);
        rs += p;
        pa[kt][g] = (_Float16)p;
      }
    rs += __shfl_xor(rs, 16);
    rs += __shfl_xor(rs, 32);
    l_run = l_run * alpha + rs;

    // rescale o (o is indexed by q = quad*4+g; alpha lives at q = l16)
    float ag[4];
#pragma unroll
    for (int g = 0; g < 4; ++g) ag[g] = __shfl(alpha, quad * 4 + g);
#pragma unroll
    for (int nt = 0; nt < 4; ++nt)
#pragma unroll
      for (int g = 0; g < 4; ++g) o[nt][g] *= ag[g];

    // ---- O += P @ V : B-frags via SCALAR Vs reads (2-way conflicts = free)
#pragma unroll
    for (int nt = 0; nt < 4; ++nt)
#pragma unroll
      for (int kt = 0; kt < 4; ++kt) {
        f16x4 bv;
#pragma unroll
        for (int j = 0; j < 4; ++j)
          bv[j] = __builtin_bit_cast(_Float16,
                    Vs[kh][(kt * 16 + quad * 4 + j) * 72 + nt * 16 + l16]);
        o[nt] = __builtin_amdgcn_mfma_f32_16x16x16f16(pa[kt], bv, o[nt], 0, 0, 0);
      }
  }

  // ---- merge the two key-half states per q-subtile, then store
  __syncthreads();
  if (kh == 1) {
    if (quad == 0) { Msc[qsub][l16] = m_run; Lsc[qsub][l16] = l_run; }
#pragma unroll
    for (int nt = 0; nt < 4; ++nt)
#pragma unroll
      for (int g = 0; g < 4; ++g)
        Osc[qsub][lane][nt * 4 + g] = (_Float16)o[nt][g];
  }
  __syncthreads();
  if (kh == 0) {
    const float m1 = Msc[qsub][l16];
    const float l1 = Lsc[qsub][l16];
    const float m  = fmaxf(m_run, m1);
    const float a0 = __expf((m_run - m) * 0.125f);
    const float a1 = __expf((m1 - m) * 0.125f);
    const float rl = 1.f / (l_run * a0 + l1 * a1);
    float a0g[4], a1g[4], rlg[4];
#pragma unroll
    for (int g = 0; g < 4; ++g) {
      a0g[g] = __shfl(a0, quad * 4 + g);
      a1g[g] = __shfl(a1, quad * 4 + g);
      rlg[g] = __shfl(rl, quad * 4 + g);
    }
#pragma unroll
    for (int g = 0; g < 4; ++g) {
      int row = qb * 64 + qsub * 16 + quad * 4 + g;
#pragma unroll
      for (int nt = 0; nt < 4; ++nt) {
        float om = o[nt][g] * a0g[g] + (float)Osc[qsub][lane][nt * 4 + g] * a1g[g];
        Ob[row * DMODEL + hc + nt * 16 + l16] = f2h(om * rlg[g]);
      }
    }
  }
}

// ---------------------------------------------------------------------------
extern "C" void kernel_launch(void* const* d_in, const int* in_sizes, int n_in,
                              void* d_out, int out_size, void* d_ws, size_t ws_size,
                              hipStream_t stream) {
  const float* q  = (const float*)d_in[0];
  const float* k  = (const float*)d_in[1];
  const float* v  = (const float*)d_in[2];
  const float* Wq = (const float*)d_in[3];
  const float* Wk = (const float*)d_in[4];
  const float* Wv = (const float*)d_in[5];
  const float* Wo = (const float*)d_in[6];
  const float* bo = (const float*)d_in[7];

  unsigned short* ws  = (unsigned short*)d_ws;
  unsigned short* Wqt = ws;                  // 512*512 fp16 each
  unsigned short* Wkt = Wqt + 262144;
  unsigned short* Wvt = Wkt + 262144;
  unsigned short* Wot = Wvt + 262144;
  unsigned short* Qb  = Wot + 262144;        // 4096*512 fp16 each
  unsigned short* Kb  = Qb + 2097152;
  unsigned short* Vb  = Kb + 2097152;
  unsigned short* Ab  = Vb + 2097152;        // attention output
  unsigned short* O1  = Kb;                  // fc1 output aliases dead Kb
  // layout byte-identical to round-2/4/9/10 proven arrangement (18.87 MB)

  wtrans_kernel<<<dim3(8, 8, 4), 256, 0, stream>>>(Wq, Wk, Wv, Wo, Wqt, Wkt, Wvt, Wot);

  // Q/K/V projections fused into one launch (z selects the op)
  gemm_kernel<<<dim3(64, 8, 3), 256, 0, stream>>>(
      q, k, v, Wqt, Wkt, Wvt, Qb, Kb, Vb, nullptr, 1, 0);

  attn_kernel<<<dim3(64, 8), 512, 0, stream>>>(Qb, Kb, Vb, Ab);

  gemm_kernel<<<dim3(64, 8, 1), 256, 0, stream>>>(
      Ab, Ab, Ab, Wot, Wot, Wot, O1, O1, O1, bo, 0, 0);
  gemm_kernel<<<dim3(64, 8, 1), 256, 0, stream>>>(
      O1, O1, O1, Wot, Wot, Wot, d_out, d_out, d_out, bo, 0, 1);
}

// Round 12
// 214.376 us; speedup vs baseline: 39.0155x; 1.0715x over previous
//
#include <hip/hip_runtime.h>

#define S_LEN  4096
#define DMODEL 512
#define NH     8
#define HD     64

typedef _Float16 f16x8 __attribute__((ext_vector_type(8)));
typedef _Float16 f16x4 __attribute__((ext_vector_type(4)));
typedef float    f32x4 __attribute__((ext_vector_type(4)));

static __device__ __forceinline__ unsigned short f2h(float x) {
  return __builtin_bit_cast(unsigned short, (_Float16)x);
}

// ---------------------------------------------------------------------------
// Weight transpose + fp32->fp16: Wt[n][k] = (fp16) W[k][n].  For z==3 (Wo)
// also emits the straight (non-transposed) fp16 copy Wof[k][n].
// grid (8,8,4) block 256   [proven + 1 extra coalesced store]
// ---------------------------------------------------------------------------
__global__ __launch_bounds__(256) void wtrans_kernel(
    const float* __restrict__ w0, const float* __restrict__ w1,
    const float* __restrict__ w2, const float* __restrict__ w3,
    unsigned short* __restrict__ o0, unsigned short* __restrict__ o1,
    unsigned short* __restrict__ o2, unsigned short* __restrict__ o3,
    unsigned short* __restrict__ o3s)
{
  __shared__ unsigned short T[64 * 72];   // T[n_local][k_local], pad 72
  const float* W; unsigned short* O;
  switch (blockIdx.z) {
    case 0:  W = w0; O = o0; break;
    case 1:  W = w1; O = o1; break;
    case 2:  W = w2; O = o2; break;
    default: W = w3; O = o3; break;
  }
  const int tid = threadIdx.x;
  const int k0 = blockIdx.x * 64, n0 = blockIdx.y * 64;
  const int c4 = (tid & 15) * 4;
#pragma unroll
  for (int rp = 0; rp < 4; ++rp) {
    int r = rp * 16 + (tid >> 4);
    float4 x = *(const float4*)(W + (k0 + r) * DMODEL + n0 + c4);
    T[(c4 + 0) * 72 + r] = f2h(x.x);
    T[(c4 + 1) * 72 + r] = f2h(x.y);
    T[(c4 + 2) * 72 + r] = f2h(x.z);
    T[(c4 + 3) * 72 + r] = f2h(x.w);
    if (blockIdx.z == 3) {
      f16x4 st;
      st[0] = (_Float16)x.x; st[1] = (_Float16)x.y;
      st[2] = (_Float16)x.z; st[3] = (_Float16)x.w;
      *(f16x4*)&o3s[(k0 + r) * DMODEL + n0 + c4] = st;
    }
  }
  __syncthreads();
#pragma unroll
  for (int it = 0; it < 2; ++it) {
    int i = tid + it * 256;
    int nl = i >> 3, c = i & 7;
    *(f16x8*)&O[(n0 + nl) * DMODEL + k0 + c * 8] = *(const f16x8*)&T[nl * 72 + c * 8];
  }
}

// ---------------------------------------------------------------------------
// bo2[col] = bo[col] + sum_j bo[j] * Wo[j][col].  grid(8) block 64.
// ---------------------------------------------------------------------------
__global__ __launch_bounds__(64) void bo2_kernel(
    const float* __restrict__ Wo, const float* __restrict__ bo,
    float* __restrict__ bo2)
{
  int col = blockIdx.x * 64 + threadIdx.x;
  float s = bo[col];
#pragma unroll 8
  for (int j = 0; j < DMODEL; ++j) s = fmaf(bo[j], Wo[j * DMODEL + col], s);
  bo2[col] = s;
}

// ---------------------------------------------------------------------------
// GEMM (multi-op): blockIdx.z selects (A,Bt,C). Body = round-2-proven kernel.
// Per-z fp32 flags via bitmasks; z==3 limited to 8 M-tiles (M=512);
// vtg != null && z==2: store transposed C (V^T) instead of row-major.
// grid (64,8,nz) block 256.
// ---------------------------------------------------------------------------
__global__ __launch_bounds__(256) void gemm_kernel(
    const void* __restrict__ A0, const void* __restrict__ A1,
    const void* __restrict__ A2, const void* __restrict__ A3,
    const unsigned short* __restrict__ B0, const unsigned short* __restrict__ B1,
    const unsigned short* __restrict__ B2, const unsigned short* __restrict__ B3,
    void* __restrict__ C0, void* __restrict__ C1,
    void* __restrict__ C2, void* __restrict__ C3,
    const float* __restrict__ bias, unsigned short* __restrict__ vtg,
    int a_fp32_mask, int c_fp32_mask)
{
  constexpr int K = DMODEL, N = DMODEL;
  __shared__ unsigned short As[64 * 32];
  __shared__ unsigned short Bs[64 * 32];
  const int z = blockIdx.z;
  if (z == 3 && blockIdx.x >= 8) return;    // Wo2 op: M = 512 only
  const void* Av; const unsigned short* Bt; void* Cv;
  switch (z) {
    case 0:  Av = A0; Bt = B0; Cv = C0; break;
    case 1:  Av = A1; Bt = B1; Cv = C1; break;
    case 2:  Av = A2; Bt = B2; Cv = C2; break;
    default: Av = A3; Bt = B3; Cv = C3; break;
  }
  const int a_fp32 = (a_fp32_mask >> z) & 1;
  const int c_fp32 = (c_fp32_mask >> z) & 1;
  const int tid  = threadIdx.x;
  const int lane = tid & 63;
  const int wid  = tid >> 6;
  const int quad = lane >> 4, l16 = lane & 15;
  const int m0 = blockIdx.x * 64, n0 = blockIdx.y * 64;
  const int wm = (wid >> 1) * 32, wn = (wid & 1) * 32;
  const int r  = tid >> 2, ck = (tid & 3) * 8;   // staging: row, k-offset
  f32x4 acc[2][2] = {};

  for (int k0 = 0; k0 < K; k0 += 32) {
    __syncthreads();
    if (a_fp32) {
      const float* p = (const float*)Av + (m0 + r) * K + k0 + ck;
      float4 x = *(const float4*)p;
      float4 y = *(const float4*)(p + 4);
      f16x8 av;
      av[0] = (_Float16)x.x; av[1] = (_Float16)x.y;
      av[2] = (_Float16)x.z; av[3] = (_Float16)x.w;
      av[4] = (_Float16)y.x; av[5] = (_Float16)y.y;
      av[6] = (_Float16)y.z; av[7] = (_Float16)y.w;
      *(f16x8*)&As[r * 32 + ck] = av;
    } else {
      *(f16x8*)&As[r * 32 + ck] =
          *(const f16x8*)((const unsigned short*)Av + (m0 + r) * K + k0 + ck);
    }
    *(f16x8*)&Bs[r * 32 + ck] = *(const f16x8*)(Bt + (n0 + r) * K + k0 + ck);
    __syncthreads();

    f16x8 a0 = *(const f16x8*)&As[(wm + l16) * 32 + quad * 8];
    f16x8 a1 = *(const f16x8*)&As[(wm + 16 + l16) * 32 + quad * 8];
    f16x8 b0 = *(const f16x8*)&Bs[(wn + l16) * 32 + quad * 8];
    f16x8 b1 = *(const f16x8*)&Bs[(wn + 16 + l16) * 32 + quad * 8];
    acc[0][0] = __builtin_amdgcn_mfma_f32_16x16x32_f16(a0, b0, acc[0][0], 0, 0, 0);
    acc[0][1] = __builtin_amdgcn_mfma_f32_16x16x32_f16(a0, b1, acc[0][1], 0, 0, 0);
    acc[1][0] = __builtin_amdgcn_mfma_f32_16x16x32_f16(a1, b0, acc[1][0], 0, 0, 0);
    acc[1][1] = __builtin_amdgcn_mfma_f32_16x16x32_f16(a1, b1, acc[1][1], 0, 0, 0);
  }

  const int do_vt = (vtg != nullptr) && (z == 2);
#pragma unroll
  for (int mt = 0; mt < 2; ++mt)
#pragma unroll
    for (int nt = 0; nt < 2; ++nt) {
      int col = n0 + wn + nt * 16 + l16;
      float bv = bias ? bias[col] : 0.f;
#pragma unroll
      for (int g = 0; g < 4; ++g) {
        int row = m0 + wm + mt * 16 + quad * 4 + g;   // C/D: row = quad*4+reg
        float val = acc[mt][nt][g] + bv;
        if (do_vt)        vtg[col * S_LEN + row] = f2h(val);      // V^T[d][key]
        else if (c_fp32)  ((float*)Cv)[row * N + col] = val;
        else              ((unsigned short*)Cv)[row * N + col] = f2h(val);
      }
    }
}

// ---------------------------------------------------------------------------
// Split-K MFMA flash attention, S^T formulation (P in registers) — round 11
// plus: Ks padded to stride 72 (kills QK^T bank conflicts) and V staged as
// V^T[d][n] from the pre-transposed global VtG, PV B-frags via f16x4 (b64)
// reads (cross-thread-staged, barrier-protected — proven-safe class).
// Block = 512 threads = 8 waves (4 q-subtiles x 2 key-halves). grid (64, 8).
// ---------------------------------------------------------------------------
__global__ __launch_bounds__(512) void attn_kernel(
    const unsigned short* __restrict__ Qb, const unsigned short* __restrict__ Kb,
    const unsigned short* __restrict__ VtG, unsigned short* __restrict__ Ob)
{
  __shared__ unsigned short Ks[2][64 * 72];   // K[n][k] per half, pad 72
  __shared__ unsigned short Vt[2][64 * 72];   // V^T[d][n] per half, pad 72
  __shared__ _Float16 Osc[4][64][16];         // merge scratch o
  __shared__ float    Msc[4][16];             // merge scratch m
  __shared__ float    Lsc[4][16];             // merge scratch l

  const int tid  = threadIdx.x;
  const int lane = tid & 63;
  const int wid  = tid >> 6;        // 0..7
  const int qsub = wid & 3;         // q-subtile
  const int kh   = wid >> 2;        // key half
  const int quad = lane >> 4, l16 = lane & 15;
  const int qb = blockIdx.x, h = blockIdx.y;
  const int hc = h * HD;

  // Persistent Q fragments (B operand): lane holds Q[q=l16][d=quad*8+j (+32)]
  const int qrow = qb * 64 + qsub * 16 + l16;
  const f16x8 bq0 = *(const f16x8*)(Qb + qrow * DMODEL + hc + quad * 8);
  const f16x8 bq1 = *(const f16x8*)(Qb + qrow * DMODEL + hc + 32 + quad * 8);

  // o[nt] holds O[q = quad*4+g][d = nt*16 + l16]
  f32x4 o[4] = {};
  float m_run = -1e30f, l_run = 0.f;   // per-lane state for q = l16

  for (int kbi = 0; kbi < 32; ++kbi) {
    __syncthreads();
    // ---- stage K[n][k] and V^T[d][n] for both halves, plain b128 writes
#pragma unroll
    for (int it = 0; it < 2; ++it) {
      int s = it * 512 + tid;                 // 0..1023
      int khs = s >> 9, n = (s >> 3) & 63, c = s & 7;
      int key = khs * 2048 + kbi * 64 + n;
      *(f16x8*)&Ks[khs][n * 72 + c * 8] =
          *(const f16x8*)(Kb + key * DMODEL + hc + c * 8);
      // n doubles as d_local for the V^T stage
      *(f16x8*)&Vt[khs][n * 72 + c * 8] =
          *(const f16x8*)(VtG + (hc + n) * S_LEN + khs * 2048 + kbi * 64 + c * 8);
    }
    __syncthreads();

    // ---- S^T = K Q^T : sT[kt][g] = S^T[key = kt*16+quad*4+g][q = l16]
    f32x4 sT[4];
#pragma unroll
    for (int kt = 0; kt < 4; ++kt) {
      f32x4 a = {};
      f16x8 ak0 = *(const f16x8*)&Ks[kh][(kt * 16 + l16) * 72 + quad * 8];
      f16x8 ak1 = *(const f16x8*)&Ks[kh][(kt * 16 + l16) * 72 + 32 + quad * 8];
      a = __builtin_amdgcn_mfma_f32_16x16x32_f16(ak0, bq0, a, 0, 0, 0);
      a = __builtin_amdgcn_mfma_f32_16x16x32_f16(ak1, bq1, a, 0, 0, 0);
      sT[kt] = a;
    }

    // ---- online softmax for column q = l16 (scale 1/8 folded into exp)
    float vmax = -1e30f;
#pragma unroll
    for (int kt = 0; kt < 4; ++kt)
#pragma unroll
      for (int g = 0; g < 4; ++g) vmax = fmaxf(vmax, sT[kt][g]);
    vmax = fmaxf(vmax, __shfl_xor(vmax, 16));
    vmax = fmaxf(vmax, __shfl_xor(vmax, 32));
    const float mn = fmaxf(m_run, vmax);
    const float alpha = __expf((m_run - mn) * 0.125f);
    m_run = mn;

    float rs = 0.f;
    f16x4 pa[4];            // P A-fragments: P[q=l16][key=kt*16+quad*4+j]
#pragma unroll
    for (int kt = 0; kt < 4; ++kt)
#pragma unroll
      for (int g = 0; g < 4; ++g) {
        float p = __expf((sT[kt][g] - mn) * 0.125f);
        rs += p;
        pa[kt][g] = (_Float16)p;
      }
    rs += __shfl_xor(rs, 16);
    rs += __shfl_xor(rs, 32);
    l_run = l_run * alpha + rs;

    // rescale o (o indexed by q = quad*4+g; alpha lives at q = l16)
    float ag[4];
#pragma unroll
    for (int g = 0; g < 4; ++g) ag[g] = __shfl(alpha, quad * 4 + g);
#pragma unroll
    for (int nt = 0; nt < 4; ++nt)
#pragma unroll
      for (int g = 0; g < 4; ++g) o[nt][g] *= ag[g];

    // ---- O += P @ V : B-frags as b64 vector reads of staged V^T
#pragma unroll
    for (int nt = 0; nt < 4; ++nt)
#pragma unroll
      for (int kt = 0; kt < 4; ++kt) {
        f16x4 bv = *(const f16x4*)&Vt[kh][(nt * 16 + l16) * 72 + kt * 16 + quad * 4];
        o[nt] = __builtin_amdgcn_mfma_f32_16x16x16f16(pa[kt], bv, o[nt], 0, 0, 0);
      }
  }

  // ---- merge the two key-half states per q-subtile, then store
  __syncthreads();
  if (kh == 1) {
    if (quad == 0) { Msc[qsub][l16] = m_run; Lsc[qsub][l16] = l_run; }
#pragma unroll
    for (int nt = 0; nt < 4; ++nt)
#pragma unroll
      for (int g = 0; g < 4; ++g)
        Osc[qsub][lane][nt * 4 + g] = (_Float16)o[nt][g];
  }
  __syncthreads();
  if (kh == 0) {
    const float m1 = Msc[qsub][l16];
    const float l1 = Lsc[qsub][l16];
    const float m  = fmaxf(m_run, m1);
    const float a0 = __expf((m_run - m) * 0.125f);
    const float a1 = __expf((m1 - m) * 0.125f);
    const float rl = 1.f / (l_run * a0 + l1 * a1);
    float a0g[4], a1g[4], rlg[4];
#pragma unroll
    for (int g = 0; g < 4; ++g) {
      a0g[g] = __shfl(a0, quad * 4 + g);
      a1g[g] = __shfl(a1, quad * 4 + g);
      rlg[g] = __shfl(rl, quad * 4 + g);
    }
#pragma unroll
    for (int g = 0; g < 4; ++g) {
      int row = qb * 64 + qsub * 16 + quad * 4 + g;
#pragma unroll
      for (int nt = 0; nt < 4; ++nt) {
        float om = o[nt][g] * a0g[g] + (float)Osc[qsub][lane][nt * 4 + g] * a1g[g];
        Ob[row * DMODEL + hc + nt * 16 + l16] = f2h(om * rlg[g]);
      }
    }
  }
}

// ---------------------------------------------------------------------------
extern "C" void kernel_launch(void* const* d_in, const int* in_sizes, int n_in,
                              void* d_out, int out_size, void* d_ws, size_t ws_size,
                              hipStream_t stream) {
  const float* q  = (const float*)d_in[0];
  const float* k  = (const float*)d_in[1];
  const float* v  = (const float*)d_in[2];
  const float* Wq = (const float*)d_in[3];
  const float* Wk = (const float*)d_in[4];
  const float* Wv = (const float*)d_in[5];
  const float* Wo = (const float*)d_in[6];
  const float* bo = (const float*)d_in[7];

  unsigned short* ws   = (unsigned short*)d_ws;
  unsigned short* Wqt  = ws;                  // 512*512 fp16 each
  unsigned short* Wkt  = Wqt  + 262144;
  unsigned short* Wvt  = Wkt  + 262144;
  unsigned short* Wot  = Wvt  + 262144;
  unsigned short* Wof  = Wot  + 262144;       // straight fp16 Wo
  unsigned short* Wo2t = Wof  + 262144;       // (Wo^2)^T fp16
  unsigned short* Qb   = Wo2t + 262144;       // 4096*512 fp16 each
  unsigned short* Kb   = Qb   + 2097152;
  unsigned short* VtG  = Kb   + 2097152;      // V^T [512][4096] fp16
  unsigned short* Ab   = VtG  + 2097152;      // attention output
  float*          bo2  = (float*)(Ab + 2097152);  // 512 f32
  // high-water ~19.0 MB (ws proven >= 23 MB by rounds 1/3 equivalence)

  wtrans_kernel<<<dim3(8, 8, 4), 256, 0, stream>>>(
      Wq, Wk, Wv, Wo, Wqt, Wkt, Wvt, Wot, Wof);

  bo2_kernel<<<dim3(8), 64, 0, stream>>>(Wo, bo, bo2);

  // z=0..2: Q/K/V projections (A fp32); z=3: Wo2t = Wot @ Wof^T (fp16, M=512)
  gemm_kernel<<<dim3(64, 8, 4), 256, 0, stream>>>(
      q, k, v, Wot, Wqt, Wkt, Wvt, Wof, Qb, Kb, nullptr, Wo2t,
      nullptr, VtG, 0x7, 0x0);

  attn_kernel<<<dim3(64, 8), 512, 0, stream>>>(Qb, Kb, VtG, Ab);

  // single fused fc_out: d_out = Ab @ Wo2 + bo2   (fp32 out)
  gemm_kernel<<<dim3(64, 8, 1), 256, 0, stream>>>(
      Ab, nullptr, nullptr, nullptr, Wo2t, nullptr, nullptr, nullptr,
      d_out, nullptr, nullptr, nullptr, bo2, nullptr, 0x0, 0x1);
}

// Round 13
// 204.867 us; speedup vs baseline: 40.8263x; 1.0464x over previous
//
#include <hip/hip_runtime.h>

#define S_LEN  4096
#define DMODEL 512
#define NH     8
#define HD     64

typedef _Float16 f16x8 __attribute__((ext_vector_type(8)));
typedef _Float16 f16x4 __attribute__((ext_vector_type(4)));
typedef float    f32x4 __attribute__((ext_vector_type(4)));

static __device__ __forceinline__ unsigned short f2h(float x) {
  return __builtin_bit_cast(unsigned short, (_Float16)x);
}

// ---------------------------------------------------------------------------
// Weight transpose + fp32->fp16: Wt[n][k] = (fp16) W[k][n].  For z==3 (Wo)
// also emits the straight fp16 copy Wof[k][n].  grid (8,8,4) block 256
// ---------------------------------------------------------------------------
__global__ __launch_bounds__(256) void wtrans_kernel(
    const float* __restrict__ w0, const float* __restrict__ w1,
    const float* __restrict__ w2, const float* __restrict__ w3,
    unsigned short* __restrict__ o0, unsigned short* __restrict__ o1,
    unsigned short* __restrict__ o2, unsigned short* __restrict__ o3,
    unsigned short* __restrict__ o3s)
{
  __shared__ unsigned short T[64 * 72];   // T[n_local][k_local], pad 72
  const float* W; unsigned short* O;
  switch (blockIdx.z) {
    case 0:  W = w0; O = o0; break;
    case 1:  W = w1; O = o1; break;
    case 2:  W = w2; O = o2; break;
    default: W = w3; O = o3; break;
  }
  const int tid = threadIdx.x;
  const int k0 = blockIdx.x * 64, n0 = blockIdx.y * 64;
  const int c4 = (tid & 15) * 4;
#pragma unroll
  for (int rp = 0; rp < 4; ++rp) {
    int r = rp * 16 + (tid >> 4);
    float4 x = *(const float4*)(W + (k0 + r) * DMODEL + n0 + c4);
    T[(c4 + 0) * 72 + r] = f2h(x.x);
    T[(c4 + 1) * 72 + r] = f2h(x.y);
    T[(c4 + 2) * 72 + r] = f2h(x.z);
    T[(c4 + 3) * 72 + r] = f2h(x.w);
    if (blockIdx.z == 3) {
      f16x4 st;
      st[0] = (_Float16)x.x; st[1] = (_Float16)x.y;
      st[2] = (_Float16)x.z; st[3] = (_Float16)x.w;
      *(f16x4*)&o3s[(k0 + r) * DMODEL + n0 + c4] = st;
    }
  }
  __syncthreads();
#pragma unroll
  for (int it = 0; it < 2; ++it) {
    int i = tid + it * 256;
    int nl = i >> 3, c = i & 7;
    *(f16x8*)&O[(n0 + nl) * DMODEL + k0 + c * 8] = *(const f16x8*)&T[nl * 72 + c * 8];
  }
}

// ---------------------------------------------------------------------------
// GEMM (multi-op): blockIdx.z selects (A,Bt,C). Body = round-2-proven kernel.
// z==3 limited to 8 M-tiles (M=512); idle z==3 blocks x in [8,16), y==0
// compute bo2 = bo + bo@Wo (folded launch). vtg!=null && z==2: C stored
// transposed (V^T).  grid (64,8,nz) block 256.
// ---------------------------------------------------------------------------
__global__ __launch_bounds__(256) void gemm_kernel(
    const void* __restrict__ A0, const void* __restrict__ A1,
    const void* __restrict__ A2, const void* __restrict__ A3,
    const unsigned short* __restrict__ B0, const unsigned short* __restrict__ B1,
    const unsigned short* __restrict__ B2, const unsigned short* __restrict__ B3,
    void* __restrict__ C0, void* __restrict__ C1,
    void* __restrict__ C2, void* __restrict__ C3,
    const float* __restrict__ bias, unsigned short* __restrict__ vtg,
    const float* __restrict__ wo_f32, const float* __restrict__ bo_in,
    float* __restrict__ bo2_out,
    int a_fp32_mask, int c_fp32_mask)
{
  constexpr int K = DMODEL, N = DMODEL;
  __shared__ unsigned short As[64 * 32];
  __shared__ unsigned short Bs[64 * 32];
  const int z = blockIdx.z;
  if (z == 3 && blockIdx.x >= 8) {          // idle tiles: bo2 side-job
    if (blockIdx.x < 16 && blockIdx.y == 0 && wo_f32) {
      int col = (blockIdx.x - 8) * 64 + (threadIdx.x & 63);
      float s = bo_in[col];
#pragma unroll 8
      for (int j = 0; j < DMODEL; ++j) s = fmaf(bo_in[j], wo_f32[j * DMODEL + col], s);
      bo2_out[col] = s;
    }
    return;
  }
  const void* Av; const unsigned short* Bt; void* Cv;
  switch (z) {
    case 0:  Av = A0; Bt = B0; Cv = C0; break;
    case 1:  Av = A1; Bt = B1; Cv = C1; break;
    case 2:  Av = A2; Bt = B2; Cv = C2; break;
    default: Av = A3; Bt = B3; Cv = C3; break;
  }
  const int a_fp32 = (a_fp32_mask >> z) & 1;
  const int c_fp32 = (c_fp32_mask >> z) & 1;
  const int tid  = threadIdx.x;
  const int lane = tid & 63;
  const int wid  = tid >> 6;
  const int quad = lane >> 4, l16 = lane & 15;
  const int m0 = blockIdx.x * 64, n0 = blockIdx.y * 64;
  const int wm = (wid >> 1) * 32, wn = (wid & 1) * 32;
  const int r  = tid >> 2, ck = (tid & 3) * 8;   // staging: row, k-offset
  f32x4 acc[2][2] = {};

  for (int k0 = 0; k0 < K; k0 += 32) {
    __syncthreads();
    if (a_fp32) {
      const float* p = (const float*)Av + (m0 + r) * K + k0 + ck;
      float4 x = *(const float4*)p;
      float4 y = *(const float4*)(p + 4);
      f16x8 av;
      av[0] = (_Float16)x.x; av[1] = (_Float16)x.y;
      av[2] = (_Float16)x.z; av[3] = (_Float16)x.w;
      av[4] = (_Float16)y.x; av[5] = (_Float16)y.y;
      av[6] = (_Float16)y.z; av[7] = (_Float16)y.w;
      *(f16x8*)&As[r * 32 + ck] = av;
    } else {
      *(f16x8*)&As[r * 32 + ck] =
          *(const f16x8*)((const unsigned short*)Av + (m0 + r) * K + k0 + ck);
    }
    *(f16x8*)&Bs[r * 32 + ck] = *(const f16x8*)(Bt + (n0 + r) * K + k0 + ck);
    __syncthreads();

    f16x8 a0 = *(const f16x8*)&As[(wm + l16) * 32 + quad * 8];
    f16x8 a1 = *(const f16x8*)&As[(wm + 16 + l16) * 32 + quad * 8];
    f16x8 b0 = *(const f16x8*)&Bs[(wn + l16) * 32 + quad * 8];
    f16x8 b1 = *(const f16x8*)&Bs[(wn + 16 + l16) * 32 + quad * 8];
    acc[0][0] = __builtin_amdgcn_mfma_f32_16x16x32_f16(a0, b0, acc[0][0], 0, 0, 0);
    acc[0][1] = __builtin_amdgcn_mfma_f32_16x16x32_f16(a0, b1, acc[0][1], 0, 0, 0);
    acc[1][0] = __builtin_amdgcn_mfma_f32_16x16x32_f16(a1, b0, acc[1][0], 0, 0, 0);
    acc[1][1] = __builtin_amdgcn_mfma_f32_16x16x32_f16(a1, b1, acc[1][1], 0, 0, 0);
  }

  const int do_vt = (vtg != nullptr) && (z == 2);
#pragma unroll
  for (int mt = 0; mt < 2; ++mt)
#pragma unroll
    for (int nt = 0; nt < 2; ++nt) {
      int col = n0 + wn + nt * 16 + l16;
      float bv = bias ? bias[col] : 0.f;
#pragma unroll
      for (int g = 0; g < 4; ++g) {
        int row = m0 + wm + mt * 16 + quad * 4 + g;   // C/D: row = quad*4+reg
        float val = acc[mt][nt][g] + bv;
        if (do_vt)        vtg[col * S_LEN + row] = f2h(val);      // V^T[d][key]
        else if (c_fp32)  ((float*)Cv)[row * N + col] = val;
        else              ((unsigned short*)Cv)[row * N + col] = f2h(val);
      }
    }
}

// ---------------------------------------------------------------------------
// Split-K MFMA flash attention, S^T formulation, 2 q-sets per wave.
// grid (32, 8), block 512 = 8 waves: 4 q-pairs (32 q: 2 reg-sets of 16)
// x 2 key-halves (2048 keys). Each Ks/Vt LDS read feeds 2 MFMAs.
// Access classes identical to round-12 (proven).
// ---------------------------------------------------------------------------
__global__ __launch_bounds__(512) void attn_kernel(
    const unsigned short* __restrict__ Qb, const unsigned short* __restrict__ Kb,
    const unsigned short* __restrict__ VtG, unsigned short* __restrict__ Ob)
{
  __shared__ unsigned short Ks[2][64 * 72];   // K[n][k] per half, pad 72
  __shared__ unsigned short Vt[2][64 * 72];   // V^T[d][n] per half, pad 72
  __shared__ _Float16 Osc[4][64][32];         // merge scratch o (2 sets)
  __shared__ float    Msc[4][2][16];          // merge scratch m
  __shared__ float    Lsc[4][2][16];          // merge scratch l

  const int tid  = threadIdx.x;
  const int lane = tid & 63;
  const int wid  = tid >> 6;        // 0..7
  const int qp   = wid & 3;         // q-pair (32 q-rows)
  const int kh   = wid >> 2;        // key half
  const int quad = lane >> 4, l16 = lane & 15;
  const int qb = blockIdx.x, h = blockIdx.y;
  const int hc = h * HD;
  const int qbase = qb * 128 + qp * 32;

  // Persistent Q fragments (B operand), 2 sets: Q[q=l16][d=quad*8+j (+32)]
  f16x8 bq[2][2];
#pragma unroll
  for (int s = 0; s < 2; ++s) {
    int qrow = qbase + s * 16 + l16;
    bq[s][0] = *(const f16x8*)(Qb + qrow * DMODEL + hc + quad * 8);
    bq[s][1] = *(const f16x8*)(Qb + qrow * DMODEL + hc + 32 + quad * 8);
  }

  // o[s][nt] holds O[q = quad*4+g][d = nt*16 + l16] for set s
  f32x4 o[2][4] = {};
  float m_run[2] = {-1e30f, -1e30f}, l_run[2] = {0.f, 0.f};

  for (int kbi = 0; kbi < 32; ++kbi) {
    __syncthreads();
    // ---- stage K[n][k] and V^T[d][n] for both halves [proven verbatim]
#pragma unroll
    for (int it = 0; it < 2; ++it) {
      int s = it * 512 + tid;                 // 0..1023
      int khs = s >> 9, n = (s >> 3) & 63, c = s & 7;
      int key = khs * 2048 + kbi * 64 + n;
      *(f16x8*)&Ks[khs][n * 72 + c * 8] =
          *(const f16x8*)(Kb + key * DMODEL + hc + c * 8);
      *(f16x8*)&Vt[khs][n * 72 + c * 8] =
          *(const f16x8*)(VtG + (hc + n) * S_LEN + khs * 2048 + kbi * 64 + c * 8);
    }
    __syncthreads();

    // ---- S^T = K Q^T : one Ks read feeds both q-sets
    f32x4 sT[2][4];
#pragma unroll
    for (int kt = 0; kt < 4; ++kt) {
      f16x8 ak0 = *(const f16x8*)&Ks[kh][(kt * 16 + l16) * 72 + quad * 8];
      f16x8 ak1 = *(const f16x8*)&Ks[kh][(kt * 16 + l16) * 72 + 32 + quad * 8];
#pragma unroll
      for (int s = 0; s < 2; ++s) {
        f32x4 a = {};
        a = __builtin_amdgcn_mfma_f32_16x16x32_f16(ak0, bq[s][0], a, 0, 0, 0);
        a = __builtin_amdgcn_mfma_f32_16x16x32_f16(ak1, bq[s][1], a, 0, 0, 0);
        sT[s][kt] = a;
      }
    }

    // ---- online softmax per set (scale 1/8 folded into exp)
    f16x4 pa[2][4];
#pragma unroll
    for (int s = 0; s < 2; ++s) {
      float vmax = -1e30f;
#pragma unroll
      for (int kt = 0; kt < 4; ++kt)
#pragma unroll
        for (int g = 0; g < 4; ++g) vmax = fmaxf(vmax, sT[s][kt][g]);
      vmax = fmaxf(vmax, __shfl_xor(vmax, 16));
      vmax = fmaxf(vmax, __shfl_xor(vmax, 32));
      const float mn = fmaxf(m_run[s], vmax);
      const float alpha = __expf((m_run[s] - mn) * 0.125f);
      m_run[s] = mn;

      float rs = 0.f;
#pragma unroll
      for (int kt = 0; kt < 4; ++kt)
#pragma unroll
        for (int g = 0; g < 4; ++g) {
          float p = __expf((sT[s][kt][g] - mn) * 0.125f);
          rs += p;
          pa[s][kt][g] = (_Float16)p;
        }
      rs += __shfl_xor(rs, 16);
      rs += __shfl_xor(rs, 32);
      l_run[s] = l_run[s] * alpha + rs;

      float ag[4];
#pragma unroll
      for (int g = 0; g < 4; ++g) ag[g] = __shfl(alpha, quad * 4 + g);
#pragma unroll
      for (int nt = 0; nt < 4; ++nt)
#pragma unroll
        for (int g = 0; g < 4; ++g) o[s][nt][g] *= ag[g];
    }

    // ---- O += P @ V : one Vt b64 read feeds both q-sets
#pragma unroll
    for (int nt = 0; nt < 4; ++nt)
#pragma unroll
      for (int kt = 0; kt < 4; ++kt) {
        f16x4 bv = *(const f16x4*)&Vt[kh][(nt * 16 + l16) * 72 + kt * 16 + quad * 4];
#pragma unroll
        for (int s = 0; s < 2; ++s)
          o[s][nt] = __builtin_amdgcn_mfma_f32_16x16x16f16(pa[s][kt], bv, o[s][nt], 0, 0, 0);
      }
  }

  // ---- merge the two key-half states per q-pair, then store
  __syncthreads();
  if (kh == 1) {
#pragma unroll
    for (int s = 0; s < 2; ++s) {
      if (quad == 0) { Msc[qp][s][l16] = m_run[s]; Lsc[qp][s][l16] = l_run[s]; }
#pragma unroll
      for (int nt = 0; nt < 4; ++nt)
#pragma unroll
        for (int g = 0; g < 4; ++g)
          Osc[qp][lane][s * 16 + nt * 4 + g] = (_Float16)o[s][nt][g];
    }
  }
  __syncthreads();
  if (kh == 0) {
#pragma unroll
    for (int s = 0; s < 2; ++s) {
      const float m1 = Msc[qp][s][l16];
      const float l1 = Lsc[qp][s][l16];
      const float m  = fmaxf(m_run[s], m1);
      const float a0 = __expf((m_run[s] - m) * 0.125f);
      const float a1 = __expf((m1 - m) * 0.125f);
      const float rl = 1.f / (l_run[s] * a0 + l1 * a1);
      float a0g[4], a1g[4], rlg[4];
#pragma unroll
      for (int g = 0; g < 4; ++g) {
        a0g[g] = __shfl(a0, quad * 4 + g);
        a1g[g] = __shfl(a1, quad * 4 + g);
        rlg[g] = __shfl(rl, quad * 4 + g);
      }
#pragma unroll
      for (int g = 0; g < 4; ++g) {
        int row = qbase + s * 16 + quad * 4 + g;
#pragma unroll
        for (int nt = 0; nt < 4; ++nt) {
          float om = o[s][nt][g] * a0g[g] + (float)Osc[qp][lane][s * 16 + nt * 4 + g] * a1g[g];
          Ob[row * DMODEL + hc + nt * 16 + l16] = f2h(om * rlg[g]);
        }
      }
    }
  }
}

// ---------------------------------------------------------------------------
extern "C" void kernel_launch(void* const* d_in, const int* in_sizes, int n_in,
                              void* d_out, int out_size, void* d_ws, size_t ws_size,
                              hipStream_t stream) {
  const float* q  = (const float*)d_in[0];
  const float* k  = (const float*)d_in[1];
  const float* v  = (const float*)d_in[2];
  const float* Wq = (const float*)d_in[3];
  const float* Wk = (const float*)d_in[4];
  const float* Wv = (const float*)d_in[5];
  const float* Wo = (const float*)d_in[6];
  const float* bo = (const float*)d_in[7];

  unsigned short* ws   = (unsigned short*)d_ws;
  unsigned short* Wqt  = ws;                  // 512*512 fp16 each
  unsigned short* Wkt  = Wqt  + 262144;
  unsigned short* Wvt  = Wkt  + 262144;
  unsigned short* Wot  = Wvt  + 262144;
  unsigned short* Wof  = Wot  + 262144;       // straight fp16 Wo
  unsigned short* Wo2t = Wof  + 262144;       // (Wo^2)^T fp16
  unsigned short* Qb   = Wo2t + 262144;       // 4096*512 fp16 each
  unsigned short* Kb   = Qb   + 2097152;
  unsigned short* VtG  = Kb   + 2097152;      // V^T [512][4096] fp16
  unsigned short* Ab   = VtG  + 2097152;      // attention output
  float*          bo2  = (float*)(Ab + 2097152);  // 512 f32
  // high-water ~19.0 MB (ws proven >= 23 MB by rounds 1/3 equivalence)

  wtrans_kernel<<<dim3(8, 8, 4), 256, 0, stream>>>(
      Wq, Wk, Wv, Wo, Wqt, Wkt, Wvt, Wot, Wof);

  // z=0..2: Q/K/V projections (A fp32; V stored transposed);
  // z=3: Wo2t = Wot @ Wof^T (M=512) + bo2 in idle tiles
  gemm_kernel<<<dim3(64, 8, 4), 256, 0, stream>>>(
      q, k, v, Wot, Wqt, Wkt, Wvt, Wof, Qb, Kb, nullptr, Wo2t,
      nullptr, VtG, Wo, bo, bo2, 0x7, 0x0);

  attn_kernel<<<dim3(32, 8), 512, 0, stream>>>(Qb, Kb, VtG, Ab);

  // single fused fc_out: d_out = Ab @ Wo2 + bo2   (fp32 out)
  gemm_kernel<<<dim3(64, 8, 1), 256, 0, stream>>>(
      Ab, nullptr, nullptr, nullptr, Wo2t, nullptr, nullptr, nullptr,
      d_out, nullptr, nullptr, nullptr, bo2, nullptr,
      nullptr, nullptr, nullptr, 0x0, 0x1);
}

// Round 14
// 200.076 us; speedup vs baseline: 41.8039x; 1.0239x over previous
//
#include <hip/hip_runtime.h>

#define S_LEN  4096
#define DMODEL 512
#define NH     8
#define HD     64

typedef _Float16 f16x8 __attribute__((ext_vector_type(8)));
typedef _Float16 f16x4 __attribute__((ext_vector_type(4)));
typedef float    f32x4 __attribute__((ext_vector_type(4)));

static __device__ __forceinline__ unsigned short f2h(float x) {
  return __builtin_bit_cast(unsigned short, (_Float16)x);
}

// ---------------------------------------------------------------------------
// Weight transpose + fp32->fp16: Wt[n][k] = (fp16) W[k][n].  For z==3 (Wo)
// also emits the straight fp16 copy Wof[k][n].  grid (8,8,4) block 256
// ---------------------------------------------------------------------------
__global__ __launch_bounds__(256) void wtrans_kernel(
    const float* __restrict__ w0, const float* __restrict__ w1,
    const float* __restrict__ w2, const float* __restrict__ w3,
    unsigned short* __restrict__ o0, unsigned short* __restrict__ o1,
    unsigned short* __restrict__ o2, unsigned short* __restrict__ o3,
    unsigned short* __restrict__ o3s)
{
  __shared__ unsigned short T[64 * 72];   // T[n_local][k_local], pad 72
  const float* W; unsigned short* O;
  switch (blockIdx.z) {
    case 0:  W = w0; O = o0; break;
    case 1:  W = w1; O = o1; break;
    case 2:  W = w2; O = o2; break;
    default: W = w3; O = o3; break;
  }
  const int tid = threadIdx.x;
  const int k0 = blockIdx.x * 64, n0 = blockIdx.y * 64;
  const int c4 = (tid & 15) * 4;
#pragma unroll
  for (int rp = 0; rp < 4; ++rp) {
    int r = rp * 16 + (tid >> 4);
    float4 x = *(const float4*)(W + (k0 + r) * DMODEL + n0 + c4);
    T[(c4 + 0) * 72 + r] = f2h(x.x);
    T[(c4 + 1) * 72 + r] = f2h(x.y);
    T[(c4 + 2) * 72 + r] = f2h(x.z);
    T[(c4 + 3) * 72 + r] = f2h(x.w);
    if (blockIdx.z == 3) {
      f16x4 st;
      st[0] = (_Float16)x.x; st[1] = (_Float16)x.y;
      st[2] = (_Float16)x.z; st[3] = (_Float16)x.w;
      *(f16x4*)&o3s[(k0 + r) * DMODEL + n0 + c4] = st;
    }
  }
  __syncthreads();
#pragma unroll
  for (int it = 0; it < 2; ++it) {
    int i = tid + it * 256;
    int nl = i >> 3, c = i & 7;
    *(f16x8*)&O[(n0 + nl) * DMODEL + k0 + c * 8] = *(const f16x8*)&T[nl * 72 + c * 8];
  }
}

// ---------------------------------------------------------------------------
// GEMM (multi-op): blockIdx.z selects (A,Bt,C). Body = round-2-proven kernel.
// z==3 limited to 8 M-tiles (M=512); idle z==3 blocks compute bo2.
// vtg!=null && z==2: C stored transposed (V^T). grid (64,8,nz) block 256.
// ---------------------------------------------------------------------------
__global__ __launch_bounds__(256) void gemm_kernel(
    const void* __restrict__ A0, const void* __restrict__ A1,
    const void* __restrict__ A2, const void* __restrict__ A3,
    const unsigned short* __restrict__ B0, const unsigned short* __restrict__ B1,
    const unsigned short* __restrict__ B2, const unsigned short* __restrict__ B3,
    void* __restrict__ C0, void* __restrict__ C1,
    void* __restrict__ C2, void* __restrict__ C3,
    const float* __restrict__ bias, unsigned short* __restrict__ vtg,
    const float* __restrict__ wo_f32, const float* __restrict__ bo_in,
    float* __restrict__ bo2_out,
    int a_fp32_mask, int c_fp32_mask)
{
  constexpr int K = DMODEL, N = DMODEL;
  __shared__ unsigned short As[64 * 32];
  __shared__ unsigned short Bs[64 * 32];
  const int z = blockIdx.z;
  if (z == 3 && blockIdx.x >= 8) {          // idle tiles: bo2 side-job
    if (blockIdx.x < 16 && blockIdx.y == 0 && wo_f32) {
      int col = (blockIdx.x - 8) * 64 + (threadIdx.x & 63);
      float s = bo_in[col];
#pragma unroll 8
      for (int j = 0; j < DMODEL; ++j) s = fmaf(bo_in[j], wo_f32[j * DMODEL + col], s);
      bo2_out[col] = s;
    }
    return;
  }
  const void* Av; const unsigned short* Bt; void* Cv;
  switch (z) {
    case 0:  Av = A0; Bt = B0; Cv = C0; break;
    case 1:  Av = A1; Bt = B1; Cv = C1; break;
    case 2:  Av = A2; Bt = B2; Cv = C2; break;
    default: Av = A3; Bt = B3; Cv = C3; break;
  }
  const int a_fp32 = (a_fp32_mask >> z) & 1;
  const int c_fp32 = (c_fp32_mask >> z) & 1;
  const int tid  = threadIdx.x;
  const int lane = tid & 63;
  const int wid  = tid >> 6;
  const int quad = lane >> 4, l16 = lane & 15;
  const int m0 = blockIdx.x * 64, n0 = blockIdx.y * 64;
  const int wm = (wid >> 1) * 32, wn = (wid & 1) * 32;
  const int r  = tid >> 2, ck = (tid & 3) * 8;   // staging: row, k-offset
  f32x4 acc[2][2] = {};

  for (int k0 = 0; k0 < K; k0 += 32) {
    __syncthreads();
    if (a_fp32) {
      const float* p = (const float*)Av + (m0 + r) * K + k0 + ck;
      float4 x = *(const float4*)p;
      float4 y = *(const float4*)(p + 4);
      f16x8 av;
      av[0] = (_Float16)x.x; av[1] = (_Float16)x.y;
      av[2] = (_Float16)x.z; av[3] = (_Float16)x.w;
      av[4] = (_Float16)y.x; av[5] = (_Float16)y.y;
      av[6] = (_Float16)y.z; av[7] = (_Float16)y.w;
      *(f16x8*)&As[r * 32 + ck] = av;
    } else {
      *(f16x8*)&As[r * 32 + ck] =
          *(const f16x8*)((const unsigned short*)Av + (m0 + r) * K + k0 + ck);
    }
    *(f16x8*)&Bs[r * 32 + ck] = *(const f16x8*)(Bt + (n0 + r) * K + k0 + ck);
    __syncthreads();

    f16x8 a0 = *(const f16x8*)&As[(wm + l16) * 32 + quad * 8];
    f16x8 a1 = *(const f16x8*)&As[(wm + 16 + l16) * 32 + quad * 8];
    f16x8 b0 = *(const f16x8*)&Bs[(wn + l16) * 32 + quad * 8];
    f16x8 b1 = *(const f16x8*)&Bs[(wn + 16 + l16) * 32 + quad * 8];
    acc[0][0] = __builtin_amdgcn_mfma_f32_16x16x32_f16(a0, b0, acc[0][0], 0, 0, 0);
    acc[0][1] = __builtin_amdgcn_mfma_f32_16x16x32_f16(a0, b1, acc[0][1], 0, 0, 0);
    acc[1][0] = __builtin_amdgcn_mfma_f32_16x16x32_f16(a1, b0, acc[1][0], 0, 0, 0);
    acc[1][1] = __builtin_amdgcn_mfma_f32_16x16x32_f16(a1, b1, acc[1][1], 0, 0, 0);
  }

  const int do_vt = (vtg != nullptr) && (z == 2);
#pragma unroll
  for (int mt = 0; mt < 2; ++mt)
#pragma unroll
    for (int nt = 0; nt < 2; ++nt) {
      int col = n0 + wn + nt * 16 + l16;
      float bv = bias ? bias[col] : 0.f;
#pragma unroll
      for (int g = 0; g < 4; ++g) {
        int row = m0 + wm + mt * 16 + quad * 4 + g;   // C/D: row = quad*4+reg
        float val = acc[mt][nt][g] + bv;
        if (do_vt)        vtg[col * S_LEN + row] = f2h(val);      // V^T[d][key]
        else if (c_fp32)  ((float*)Cv)[row * N + col] = val;
        else              ((unsigned short*)Cv)[row * N + col] = f2h(val);
      }
    }
}

// ---------------------------------------------------------------------------
// Split-K MFMA flash attention, S^T formulation, 2 q-sets per wave,
// register-prefetched staging. Block = 256 threads = 4 waves:
// 2 q-pairs (32 q each) x 2 key-halves (2048 keys). grid (64, 8) =
// 512 blocks = 2 blocks/CU (cross-block latency overlap) while keeping
// round-13's 2-MFMAs-per-LDS-read intensity. Next iteration's global
// loads are issued into registers before compute (latency hidden).
// ---------------------------------------------------------------------------
__global__ __launch_bounds__(256) void attn_kernel(
    const unsigned short* __restrict__ Qb, const unsigned short* __restrict__ Kb,
    const unsigned short* __restrict__ VtG, unsigned short* __restrict__ Ob)
{
  __shared__ unsigned short Ks[2][64 * 72];   // K[n][k] per half, pad 72
  __shared__ unsigned short Vt[2][64 * 72];   // V^T[d][n] per half, pad 72
  __shared__ _Float16 Osc[2][64][32];         // merge scratch o (2 sets)
  __shared__ float    Msc[2][2][16];          // merge scratch m
  __shared__ float    Lsc[2][2][16];          // merge scratch l

  const int tid  = threadIdx.x;
  const int lane = tid & 63;
  const int wid  = tid >> 6;        // 0..3
  const int qp   = wid & 1;         // q-pair (32 q-rows)
  const int kh   = wid >> 1;        // key half
  const int quad = lane >> 4, l16 = lane & 15;
  const int qb = blockIdx.x, h = blockIdx.y;
  const int hc = h * HD;
  const int qbase = qb * 64 + qp * 32;

  // Persistent Q fragments (B operand), 2 sets: Q[q=l16][d=quad*8+j (+32)]
  f16x8 bq[2][2];
#pragma unroll
  for (int s = 0; s < 2; ++s) {
    int qrow = qbase + s * 16 + l16;
    bq[s][0] = *(const f16x8*)(Qb + qrow * DMODEL + hc + quad * 8);
    bq[s][1] = *(const f16x8*)(Qb + qrow * DMODEL + hc + 32 + quad * 8);
  }

  // o[s][nt] holds O[q = quad*4+g][d = nt*16 + l16] for set s
  f32x4 o[2][4] = {};
  float m_run[2] = {-1e30f, -1e30f}, l_run[2] = {0.f, 0.f};

  // staging decomposition (256 threads, 1024 chunks per array):
  // it in 0..3: s = it*256+tid; khs = s>>9; n = (s>>3)&63; c = s&7
  f16x8 kreg[4], vreg[4];
#pragma unroll
  for (int it = 0; it < 4; ++it) {     // prefetch kbi = 0
    int s = it * 256 + tid;
    int khs = s >> 9, n = (s >> 3) & 63, c = s & 7;
    kreg[it] = *(const f16x8*)(Kb + (khs * 2048 + n) * DMODEL + hc + c * 8);
    vreg[it] = *(const f16x8*)(VtG + (hc + n) * S_LEN + khs * 2048 + c * 8);
  }

  for (int kbi = 0; kbi < 32; ++kbi) {
    __syncthreads();                   // all waves done reading previous tiles
#pragma unroll
    for (int it = 0; it < 4; ++it) {
      int s = it * 256 + tid;
      int khs = s >> 9, n = (s >> 3) & 63, c = s & 7;
      *(f16x8*)&Ks[khs][n * 72 + c * 8] = kreg[it];
      *(f16x8*)&Vt[khs][n * 72 + c * 8] = vreg[it];
    }
    __syncthreads();                   // staging visible

    if (kbi + 1 < 32) {                // prefetch next chunk into registers
      int kb1 = (kbi + 1) * 64;
#pragma unroll
      for (int it = 0; it < 4; ++it) {
        int s = it * 256 + tid;
        int khs = s >> 9, n = (s >> 3) & 63, c = s & 7;
        kreg[it] = *(const f16x8*)(Kb + (khs * 2048 + kb1 + n) * DMODEL + hc + c * 8);
        vreg[it] = *(const f16x8*)(VtG + (hc + n) * S_LEN + khs * 2048 + kb1 + c * 8);
      }
    }

    // ---- S^T = K Q^T : one Ks read feeds both q-sets
    f32x4 sT[2][4];
#pragma unroll
    for (int kt = 0; kt < 4; ++kt) {
      f16x8 ak0 = *(const f16x8*)&Ks[kh][(kt * 16 + l16) * 72 + quad * 8];
      f16x8 ak1 = *(const f16x8*)&Ks[kh][(kt * 16 + l16) * 72 + 32 + quad * 8];
#pragma unroll
      for (int s = 0; s < 2; ++s) {
        f32x4 a = {};
        a = __builtin_amdgcn_mfma_f32_16x16x32_f16(ak0, bq[s][0], a, 0, 0, 0);
        a = __builtin_amdgcn_mfma_f32_16x16x32_f16(ak1, bq[s][1], a, 0, 0, 0);
        sT[s][kt] = a;
      }
    }

    // ---- online softmax per set (scale 1/8 folded into exp)
    f16x4 pa[2][4];
#pragma unroll
    for (int s = 0; s < 2; ++s) {
      float vmax = -1e30f;
#pragma unroll
      for (int kt = 0; kt < 4; ++kt)
#pragma unroll
        for (int g = 0; g < 4; ++g) vmax = fmaxf(vmax, sT[s][kt][g]);
      vmax = fmaxf(vmax, __shfl_xor(vmax, 16));
      vmax = fmaxf(vmax, __shfl_xor(vmax, 32));
      const float mn = fmaxf(m_run[s], vmax);
      const float alpha = __expf((m_run[s] - mn) * 0.125f);
      m_run[s] = mn;

      float rs = 0.f;
#pragma unroll
      for (int kt = 0; kt < 4; ++kt)
#pragma unroll
        for (int g = 0; g < 4; ++g) {
          float p = __expf((sT[s][kt][g] - mn) * 0.125f);
          rs += p;
          pa[s][kt][g] = (_Float16)p;
        }
      rs += __shfl_xor(rs, 16);
      rs += __shfl_xor(rs, 32);
      l_run[s] = l_run[s] * alpha + rs;

      float ag[4];
#pragma unroll
      for (int g = 0; g < 4; ++g) ag[g] = __shfl(alpha, quad * 4 + g);
#pragma unroll
      for (int nt = 0; nt < 4; ++nt)
#pragma unroll
        for (int g = 0; g < 4; ++g) o[s][nt][g] *= ag[g];
    }

    // ---- O += P @ V : one Vt b64 read feeds both q-sets
#pragma unroll
    for (int nt = 0; nt < 4; ++nt)
#pragma unroll
      for (int kt = 0; kt < 4; ++kt) {
        f16x4 bv = *(const f16x4*)&Vt[kh][(nt * 16 + l16) * 72 + kt * 16 + quad * 4];
#pragma unroll
        for (int s = 0; s < 2; ++s)
          o[s][nt] = __builtin_amdgcn_mfma_f32_16x16x16f16(pa[s][kt], bv, o[s][nt], 0, 0, 0);
      }
  }

  // ---- merge the two key-half states per q-pair, then store
  __syncthreads();
  if (kh == 1) {
#pragma unroll
    for (int s = 0; s < 2; ++s) {
      if (quad == 0) { Msc[qp][s][l16] = m_run[s]; Lsc[qp][s][l16] = l_run[s]; }
#pragma unroll
      for (int nt = 0; nt < 4; ++nt)
#pragma unroll
        for (int g = 0; g < 4; ++g)
          Osc[qp][lane][s * 16 + nt * 4 + g] = (_Float16)o[s][nt][g];
    }
  }
  __syncthreads();
  if (kh == 0) {
#pragma unroll
    for (int s = 0; s < 2; ++s) {
      const float m1 = Msc[qp][s][l16];
      const float l1 = Lsc[qp][s][l16];
      const float m  = fmaxf(m_run[s], m1);
      const float a0 = __expf((m_run[s] - m) * 0.125f);
      const float a1 = __expf((m1 - m) * 0.125f);
      const float rl = 1.f / (l_run[s] * a0 + l1 * a1);
      float a0g[4], a1g[4], rlg[4];
#pragma unroll
      for (int g = 0; g < 4; ++g) {
        a0g[g] = __shfl(a0, quad * 4 + g);
        a1g[g] = __shfl(a1, quad * 4 + g);
        rlg[g] = __shfl(rl, quad * 4 + g);
      }
#pragma unroll
      for (int g = 0; g < 4; ++g) {
        int row = qbase + s * 16 + quad * 4 + g;
#pragma unroll
        for (int nt = 0; nt < 4; ++nt) {
          float om = o[s][nt][g] * a0g[g] + (float)Osc[qp][lane][s * 16 + nt * 4 + g] * a1g[g];
          Ob[row * DMODEL + hc + nt * 16 + l16] = f2h(om * rlg[g]);
        }
      }
    }
  }
}

// ---------------------------------------------------------------------------
extern "C" void kernel_launch(void* const* d_in, const int* in_sizes, int n_in,
                              void* d_out, int out_size, void* d_ws, size_t ws_size,
                              hipStream_t stream) {
  const float* q  = (const float*)d_in[0];
  const float* k  = (const float*)d_in[1];
  const float* v  = (const float*)d_in[2];
  const float* Wq = (const float*)d_in[3];
  const float* Wk = (const float*)d_in[4];
  const float* Wv = (const float*)d_in[5];
  const float* Wo = (const float*)d_in[6];
  const float* bo = (const float*)d_in[7];

  unsigned short* ws   = (unsigned short*)d_ws;
  unsigned short* Wqt  = ws;                  // 512*512 fp16 each
  unsigned short* Wkt  = Wqt  + 262144;
  unsigned short* Wvt  = Wkt  + 262144;
  unsigned short* Wot  = Wvt  + 262144;
  unsigned short* Wof  = Wot  + 262144;       // straight fp16 Wo
  unsigned short* Wo2t = Wof  + 262144;       // (Wo^2)^T fp16
  unsigned short* Qb   = Wo2t + 262144;       // 4096*512 fp16 each
  unsigned short* Kb   = Qb   + 2097152;
  unsigned short* VtG  = Kb   + 2097152;      // V^T [512][4096] fp16
  unsigned short* Ab   = VtG  + 2097152;      // attention output
  float*          bo2  = (float*)(Ab + 2097152);  // 512 f32
  // high-water ~19.0 MB (ws proven >= 23 MB by rounds 1/3 equivalence)

  wtrans_kernel<<<dim3(8, 8, 4), 256, 0, stream>>>(
      Wq, Wk, Wv, Wo, Wqt, Wkt, Wvt, Wot, Wof);

  // z=0..2: Q/K/V projections (A fp32; V stored transposed);
  // z=3: Wo2t = Wot @ Wof^T (M=512) + bo2 in idle tiles
  gemm_kernel<<<dim3(64, 8, 4), 256, 0, stream>>>(
      q, k, v, Wot, Wqt, Wkt, Wvt, Wof, Qb, Kb, nullptr, Wo2t,
      nullptr, VtG, Wo, bo, bo2, 0x7, 0x0);

  attn_kernel<<<dim3(64, 8), 256, 0, stream>>>(Qb, Kb, VtG, Ab);

  // single fused fc_out: d_out = Ab @ Wo2 + bo2   (fp32 out)
  gemm_kernel<<<dim3(64, 8, 1), 256, 0, stream>>>(
      Ab, nullptr, nullptr, nullptr, Wo2t, nullptr, nullptr, nullptr,
      d_out, nullptr, nullptr, nullptr, bo2, nullptr,
      nullptr, nullptr, nullptr, 0x0, 0x1);
}